// Round 4
// baseline (988.408 us; speedup 1.0000x reference)
//
#include <hip/hip_runtime.h>

#define DD 64
#define XPAD 68   // padded leading dim for transposed input tile

typedef unsigned int u32;

// ---------------- preprocessing: bucket CSR, key = dst*R + ty ----------------

__global__ __launch_bounds__(256) void zero_u32_kernel(u32* __restrict__ p, int n) {
  int i = blockIdx.x * 256 + threadIdx.x;
  if (i < n) p[i] = 0u;
}

__global__ __launch_bounds__(256) void hist_kernel(const int* __restrict__ edst,
                                                   const int* __restrict__ et,
                                                   u32* __restrict__ cnt, int E, int R) {
  int e = blockIdx.x * 256 + threadIdx.x;
  if (e < E) atomicAdd(&cnt[(size_t)edst[e] * R + et[e]], 1u);
}

// Per-block inclusive scan of 1024 counts -> exclusive row_ptr; block totals out.
__global__ __launch_bounds__(1024) void scan1_kernel(const u32* __restrict__ cnt,
                                                     u32* __restrict__ row_ptr,
                                                     u32* __restrict__ partials, int M) {
  __shared__ u32 s[1024];
  int t = threadIdx.x;
  int gid = blockIdx.x * 1024 + t;
  u32 v = (gid < M) ? cnt[gid] : 0u;
  s[t] = v;
  __syncthreads();
  for (int off = 1; off < 1024; off <<= 1) {
    u32 x = (t >= off) ? s[t - off] : 0u;
    __syncthreads();
    s[t] += x;
    __syncthreads();
  }
  if (gid < M) row_ptr[gid] = s[t] - v;          // exclusive within block
  if (t == 1023) partials[blockIdx.x] = s[1023]; // block total
}

// Single-block parallel exclusive scan of up to 1024 partials.
__global__ __launch_bounds__(1024) void scan2_kernel(u32* __restrict__ partials, int nb) {
  __shared__ u32 s[1024];
  int t = threadIdx.x;
  u32 v = (t < nb) ? partials[t] : 0u;
  s[t] = v;
  __syncthreads();
  for (int off = 1; off < 1024; off <<= 1) {
    u32 x = (t >= off) ? s[t - off] : 0u;
    __syncthreads();
    s[t] += x;
    __syncthreads();
  }
  if (t < nb) partials[t] = s[t] - v;            // exclusive
}

__global__ __launch_bounds__(1024) void scan3_kernel(u32* __restrict__ row_ptr,
                                                     const u32* __restrict__ partials,
                                                     int M, int E) {
  int gid = blockIdx.x * 1024 + threadIdx.x;
  if (gid < M) row_ptr[gid] += partials[blockIdx.x];
  else if (gid == M) row_ptr[M] = (u32)E;
}

__global__ __launch_bounds__(256) void scatter_kernel(const int* __restrict__ esrc,
                                                      const int* __restrict__ edst,
                                                      const int* __restrict__ et,
                                                      const u32* __restrict__ row_ptr,
                                                      u32* __restrict__ fill,
                                                      u32* __restrict__ packed, int E, int R) {
  int e = blockIdx.x * 256 + threadIdx.x;
  if (e >= E) return;
  size_t key = (size_t)edst[e] * R + et[e];
  u32 pos = row_ptr[key] + atomicAdd(&fill[key], 1u);
  packed[pos] = (u32)esrc[e];
}

// ---------------- per-layer compute ----------------

// W[r,i,o] = sum_b coeff[r,b] * basis[b,i,o]
__global__ __launch_bounds__(256) void compute_w_kernel(
    const float* __restrict__ basis, const float* __restrict__ coeff,
    float* __restrict__ W, int Rn, int Bn) {
  int idx = blockIdx.x * 256 + threadIdx.x;
  if (idx >= Rn * DD * DD) return;
  int r = idx / (DD * DD);
  int io = idx - r * DD * DD;
  float acc = 0.f;
  for (int b = 0; b < Bn; ++b)
    acc += coeff[r * Bn + b] * basis[b * DD * DD + io];
  W[idx] = acc;
}

// One wave per destination node; lane = feature. Per-relation segment sums of x.
__global__ __launch_bounds__(256) void aggregate_kernel(
    const u32* __restrict__ packed, const u32* __restrict__ row_ptr,
    const float* __restrict__ x, float* __restrict__ agg,
    int N, int R, int r0, int r1) {
  int wid  = (blockIdx.x * 256 + threadIdx.x) >> 6;
  int lane = threadIdx.x & 63;
  if (wid >= N) return;
  const u32* rp = row_ptr + (size_t)wid * R;
  u32 beg = rp[r0];
  for (int r = r0; r < r1; ++r) {
    u32 end = rp[r + 1];
    float s = 0.f;
    for (u32 e = beg; e < end; ++e)
      s += x[(size_t)packed[e] * DD + lane];
    agg[((size_t)(r - r0) * N + wid) * DD + lane] = s;
    beg = end;
  }
}

// out = [relu](Sum_m aggchunk_m @ W_m  [+ x@self_w + bias if first] [+ out if !first])
__global__ __launch_bounds__(256) void transform_kernel(
    const float* __restrict__ x, const float* __restrict__ aggchunk,
    const float* __restrict__ Wchunk, const float* __restrict__ self_w,
    const float* __restrict__ bias_l, float* __restrict__ out,
    int N, int cs, int first, int last) {
  __shared__ __align__(16) float Ws[DD * DD];
  __shared__ __align__(16) float xsT[DD * XPAD];

  const int t = threadIdx.x;
  const int nbase = blockIdx.x * DD;
  const int o0 = (t & 15) * 4;
  const int n0 = (t >> 4) * 4;

  float acc[4][4];
#pragma unroll
  for (int a = 0; a < 4; ++a)
#pragma unroll
    for (int b = 0; b < 4; ++b) acc[a][b] = 0.f;

  const int nm = cs + (first ? 1 : 0);
  for (int m = 0; m < nm; ++m) {
    const bool is_self = (m == cs);
    const float* src  = is_self ? x : (aggchunk + (size_t)m * N * DD);
    const float* Wsrc = is_self ? self_w : (Wchunk + (size_t)m * DD * DD);

    for (int j = t; j < DD * DD; j += 256) Ws[j] = Wsrc[j];
    for (int j = t; j < DD * DD; j += 256) {
      int nl = j >> 6;
      int i  = j & 63;
      int n  = nbase + nl;
      xsT[i * XPAD + nl] = (n < N) ? src[(size_t)n * DD + i] : 0.f;
    }
    __syncthreads();

#pragma unroll 4
    for (int i = 0; i < DD; ++i) {
      float4 wv = *reinterpret_cast<const float4*>(&Ws[i * DD + o0]);
      float4 xv = *reinterpret_cast<const float4*>(&xsT[i * XPAD + n0]);
      float xa[4] = {xv.x, xv.y, xv.z, xv.w};
      float wa[4] = {wv.x, wv.y, wv.z, wv.w};
#pragma unroll
      for (int a = 0; a < 4; ++a)
#pragma unroll
        for (int b = 0; b < 4; ++b) acc[a][b] += xa[a] * wa[b];
    }
    __syncthreads();
  }

  float4 bv = make_float4(0.f, 0.f, 0.f, 0.f);
  if (first) bv = *reinterpret_cast<const float4*>(&bias_l[o0]);

#pragma unroll
  for (int a = 0; a < 4; ++a) {
    int n = nbase + n0 + a;
    if (n < N) {
      float* op = &out[(size_t)n * DD + o0];
      float4 res = make_float4(acc[a][0] + bv.x, acc[a][1] + bv.y,
                               acc[a][2] + bv.z, acc[a][3] + bv.w);
      if (!first) {
        float4 prev = *reinterpret_cast<const float4*>(op);
        res.x += prev.x; res.y += prev.y; res.z += prev.z; res.w += prev.w;
      }
      if (last) {
        res.x = fmaxf(res.x, 0.f); res.y = fmaxf(res.y, 0.f);
        res.z = fmaxf(res.z, 0.f); res.w = fmaxf(res.w, 0.f);
      }
      *reinterpret_cast<float4*>(op) = res;
    }
  }
}

extern "C" void kernel_launch(void* const* d_in, const int* in_sizes, int n_in,
                              void* d_out, int out_size, void* d_ws, size_t ws_size,
                              hipStream_t stream) {
  const float* x0     = (const float*)d_in[0];
  const float* basis  = (const float*)d_in[1];
  const float* coeff  = (const float*)d_in[2];
  const float* self_w = (const float*)d_in[3];
  const float* bias   = (const float*)d_in[4];
  const int*   eidx   = (const int*)d_in[5];
  const int*   etyp   = (const int*)d_in[6];

  const int N  = in_sizes[0] / DD;
  const int L  = in_sizes[4] / DD;
  const int Bn = in_sizes[1] / (L * DD * DD);
  const int R  = in_sizes[2] / (L * Bn);
  const int E  = in_sizes[6];
  const size_t M = (size_t)N * R;       // bucket-CSR rows

  const int* esrc = eidx;
  const int* edst = eidx + E;

  // ---- workspace layout ----
  u32* row_ptr = (u32*)d_ws;                             // M+1
  u32* packed  = row_ptr + M + 1;                        // E
  size_t u32B  = ((M + 1 + (size_t)E) * 4 + 15) / 16 * 16;
  float* Wbuf  = (float*)((char*)d_ws + u32B);           // R*DD*DD
  float* A     = Wbuf + (size_t)R * DD * DD;             // N*DD
  float* agg   = A + (size_t)N * DD;                     // chunk*N*DD
  // build-phase overlays (agg region unused until layers start)
  u32* cnt      = (u32*)agg;                             // M
  u32* fill     = cnt + M;                               // M
  // chunk sizing
  size_t availF = ws_size / sizeof(float);
  size_t fixedF = u32B / 4 + (size_t)R * DD * DD + (size_t)N * DD;
  int chunk = 1;
  if (availF > fixedF + (size_t)N * DD) {
    size_t c = (availF - fixedF) / ((size_t)N * DD);
    chunk = (int)(c > (size_t)R ? (size_t)R : c);
  }
  // partials go after fill if chunk region is big enough, else reuse A
  u32* partials = (chunk * (size_t)N * DD * 4 >= (2 * M + 1024) * 4)
                      ? (fill + M) : (u32*)A;

  const int NB_SCAN = (int)((M + 1023) / 1024);
  const int NB3     = (int)((M + 1 + 1023) / 1024);
  const int nb_x    = (N + DD - 1) / DD;
  const int nb_e    = (E + 255) / 256;
  const int nb_agg  = (int)(((size_t)N * 64 + 255) / 256);

  // ---- build bucket CSR (once; edges constant across layers) ----
  zero_u32_kernel<<<(int)((2 * M + 255) / 256), 256, 0, stream>>>(cnt, (int)(2 * M));
  hist_kernel<<<nb_e, 256, 0, stream>>>(edst, etyp, cnt, E, R);
  scan1_kernel<<<NB_SCAN, 1024, 0, stream>>>(cnt, row_ptr, partials, (int)M);
  scan2_kernel<<<1, 1024, 0, stream>>>(partials, NB_SCAN);
  scan3_kernel<<<NB3, 1024, 0, stream>>>(row_ptr, partials, (int)M, E);
  scatter_kernel<<<nb_e, 256, 0, stream>>>(esrc, edst, etyp, row_ptr, fill, packed, E, R);

  // ---- layers ----
  for (int l = 0; l < L; ++l) {
    const float* xin = (l == 0) ? x0 : A;
    float* outf      = (l == L - 1) ? (float*)d_out : A;

    compute_w_kernel<<<(R * DD * DD + 255) / 256, 256, 0, stream>>>(
        basis + (size_t)l * Bn * DD * DD, coeff + (size_t)l * R * Bn, Wbuf, R, Bn);

    for (int c0 = 0; c0 < R; c0 += chunk) {
      int cs = (R - c0 < chunk) ? (R - c0) : chunk;
      int first = (c0 == 0) ? 1 : 0;
      int last  = (c0 + cs >= R) ? 1 : 0;
      aggregate_kernel<<<nb_agg, 256, 0, stream>>>(
          packed, row_ptr, xin, agg, N, R, c0, c0 + cs);
      transform_kernel<<<nb_x, 256, 0, stream>>>(
          xin, agg, Wbuf + (size_t)c0 * DD * DD, self_w + (size_t)l * DD * DD,
          bias + (size_t)l * DD, outf, N, cs, first, last);
    }
  }
}

// Round 5
// 927.510 us; speedup vs baseline: 1.0657x; 1.0657x over previous
//
#include <hip/hip_runtime.h>

#define DD 64
#define XPAD 68   // padded leading dim for transposed LDS tile

typedef unsigned int u32;

// ---------------- preprocessing: bucket CSR, key = dst*R + ty ----------------

__global__ __launch_bounds__(256) void zero_u32_kernel(u32* __restrict__ p, int n) {
  int i = blockIdx.x * 256 + threadIdx.x;
  if (i < n) p[i] = 0u;
}

__global__ __launch_bounds__(256) void hist_kernel(const int* __restrict__ edst,
                                                   const int* __restrict__ et,
                                                   u32* __restrict__ cnt, int E, int R) {
  int e = blockIdx.x * 256 + threadIdx.x;
  if (e < E) atomicAdd(&cnt[(size_t)edst[e] * R + et[e]], 1u);
}

__global__ __launch_bounds__(1024) void scan1_kernel(const u32* __restrict__ cnt,
                                                     u32* __restrict__ row_ptr,
                                                     u32* __restrict__ partials, int M) {
  __shared__ u32 s[1024];
  int t = threadIdx.x;
  int gid = blockIdx.x * 1024 + t;
  u32 v = (gid < M) ? cnt[gid] : 0u;
  s[t] = v;
  __syncthreads();
  for (int off = 1; off < 1024; off <<= 1) {
    u32 x = (t >= off) ? s[t - off] : 0u;
    __syncthreads();
    s[t] += x;
    __syncthreads();
  }
  if (gid < M) row_ptr[gid] = s[t] - v;          // exclusive within block
  if (t == 1023) partials[blockIdx.x] = s[1023]; // block total
}

__global__ __launch_bounds__(1024) void scan2_kernel(u32* __restrict__ partials, int nb) {
  __shared__ u32 s[1024];
  int t = threadIdx.x;
  u32 v = (t < nb) ? partials[t] : 0u;
  s[t] = v;
  __syncthreads();
  for (int off = 1; off < 1024; off <<= 1) {
    u32 x = (t >= off) ? s[t - off] : 0u;
    __syncthreads();
    s[t] += x;
    __syncthreads();
  }
  if (t < nb) partials[t] = s[t] - v;            // exclusive
}

__global__ __launch_bounds__(1024) void scan3_kernel(u32* __restrict__ row_ptr,
                                                     const u32* __restrict__ partials,
                                                     int M, int E) {
  int gid = blockIdx.x * 1024 + threadIdx.x;
  if (gid < M) row_ptr[gid] += partials[blockIdx.x];
  else if (gid == M) row_ptr[M] = (u32)E;
}

__global__ __launch_bounds__(256) void scatter_kernel(const int* __restrict__ esrc,
                                                      const int* __restrict__ edst,
                                                      const int* __restrict__ et,
                                                      const u32* __restrict__ row_ptr,
                                                      u32* __restrict__ fill,
                                                      u32* __restrict__ packed, int E, int R) {
  int e = blockIdx.x * 256 + threadIdx.x;
  if (e >= E) return;
  size_t key = (size_t)edst[e] * R + et[e];
  u32 pos = row_ptr[key] + atomicAdd(&fill[key], 1u);
  packed[pos] = (u32)esrc[e];
}

// ---------------- per-layer compute ----------------

// W[r,i,o] = sum_b coeff[r,b] * basis[b,i,o]
__global__ __launch_bounds__(256) void compute_w_kernel(
    const float* __restrict__ basis, const float* __restrict__ coeff,
    float* __restrict__ W, int Rn, int Bn) {
  int idx = blockIdx.x * 256 + threadIdx.x;
  if (idx >= Rn * DD * DD) return;
  int r = idx / (DD * DD);
  int io = idx - r * DD * DD;
  float acc = 0.f;
  for (int b = 0; b < Bn; ++b)
    acc += coeff[r * Bn + b] * basis[b * DD * DD + io];
  W[idx] = acc;
}

// Fused: per 64-dst-node tile, for m = 0..R (R relations + self):
//   phase A: segment-sum x rows into transposed LDS tile (or stream x for self)
//   phase B: register-tiled 64x64x64 GEMM accumulate
// epilogue: + bias, ReLU, single float4 store.
__global__ __launch_bounds__(256) void fused_layer_kernel(
    const float* __restrict__ x,        // [N,D] layer input
    const u32*   __restrict__ packed,   // [E] src ids, bucket-sorted by dst*R+ty
    const u32*   __restrict__ row_ptr,  // [N*R+1]
    const float* __restrict__ W,        // [R,D,D]
    const float* __restrict__ self_w,   // [D,D]
    const float* __restrict__ bias_l,   // [D]
    float* __restrict__ out,            // [N,D]
    int N, int R) {
  __shared__ __align__(16) float Ws[DD * DD];
  __shared__ __align__(16) float aggT[DD * XPAD];   // [feature][node_local]
  __shared__ u32 rps[DD * 8 + 1];                   // row_ptr slice for this tile

  const int t     = threadIdx.x;
  const int w     = t >> 6;        // wave 0..3
  const int lane  = t & 63;        // = feature index in phase A
  const int nbase = blockIdx.x * DD;
  const size_t Mtot = (size_t)N * R;

  // stage row_ptr slice: indices nbase*R + [0, 64*R]
  for (int j = t; j < DD * 8 + 1; j += 256) {
    size_t idx = (size_t)nbase * R + j;
    rps[j] = (idx <= Mtot) ? row_ptr[idx] : row_ptr[Mtot];
  }
  __syncthreads();

  const int o0 = (t & 15) * 4;   // 4 consecutive outputs
  const int n0 = (t >> 4) * 4;   // 4 consecutive local nodes

  float acc[4][4];
#pragma unroll
  for (int a = 0; a < 4; ++a)
#pragma unroll
    for (int b = 0; b < 4; ++b) acc[a][b] = 0.f;

  for (int m = 0; m <= R; ++m) {
    if (m) __syncthreads();   // previous GEMM done before overwriting LDS

    // load weight matrix m
    const float* Wsrc = (m == R) ? self_w : (W + (size_t)m * DD * DD);
    for (int j = t; j < DD * DD; j += 256) Ws[j] = Wsrc[j];

    // phase A: fill transposed source tile
    if (m < R) {
#pragma unroll 4
      for (int k = 0; k < 16; ++k) {
        int nl = w * 16 + k;
        int n  = nbase + nl;
        float s0 = 0.f, s1 = 0.f;
        if (n < N) {
          u32 b = rps[nl * 8 + m];
          u32 e = rps[nl * 8 + m + 1];
          u32 i = b;
          for (; i + 1 < e; i += 2) {
            s0 += x[(size_t)packed[i] * DD + lane];
            s1 += x[(size_t)packed[i + 1] * DD + lane];
          }
          if (i < e) s0 += x[(size_t)packed[i] * DD + lane];
        }
        aggT[lane * XPAD + nl] = s0 + s1;
      }
    } else {
#pragma unroll 4
      for (int k = 0; k < 16; ++k) {
        int nl = w * 16 + k;
        int n  = nbase + nl;
        aggT[lane * XPAD + nl] = (n < N) ? x[(size_t)n * DD + lane] : 0.f;
      }
    }
    __syncthreads();

    // phase B: GEMM accumulate
#pragma unroll 4
    for (int i = 0; i < DD; ++i) {
      float4 wv = *reinterpret_cast<const float4*>(&Ws[i * DD + o0]);
      float4 xv = *reinterpret_cast<const float4*>(&aggT[i * XPAD + n0]);
      float xa[4] = {xv.x, xv.y, xv.z, xv.w};
      float wa[4] = {wv.x, wv.y, wv.z, wv.w};
#pragma unroll
      for (int a = 0; a < 4; ++a)
#pragma unroll
        for (int b = 0; b < 4; ++b) acc[a][b] += xa[a] * wa[b];
    }
  }

  // epilogue: bias + relu + store
  float4 bv = *reinterpret_cast<const float4*>(&bias_l[o0]);
#pragma unroll
  for (int a = 0; a < 4; ++a) {
    int n = nbase + n0 + a;
    if (n < N) {
      float4 res = make_float4(fmaxf(acc[a][0] + bv.x, 0.f),
                               fmaxf(acc[a][1] + bv.y, 0.f),
                               fmaxf(acc[a][2] + bv.z, 0.f),
                               fmaxf(acc[a][3] + bv.w, 0.f));
      *reinterpret_cast<float4*>(&out[(size_t)n * DD + o0]) = res;
    }
  }
}

extern "C" void kernel_launch(void* const* d_in, const int* in_sizes, int n_in,
                              void* d_out, int out_size, void* d_ws, size_t ws_size,
                              hipStream_t stream) {
  const float* x0     = (const float*)d_in[0];
  const float* basis  = (const float*)d_in[1];
  const float* coeff  = (const float*)d_in[2];
  const float* self_w = (const float*)d_in[3];
  const float* bias   = (const float*)d_in[4];
  const int*   eidx   = (const int*)d_in[5];
  const int*   etyp   = (const int*)d_in[6];

  const int N  = in_sizes[0] / DD;
  const int L  = in_sizes[4] / DD;
  const int Bn = in_sizes[1] / (L * DD * DD);
  const int R  = in_sizes[2] / (L * Bn);
  const int E  = in_sizes[6];
  const size_t M = (size_t)N * R;       // bucket-CSR rows

  const int* esrc = eidx;
  const int* edst = eidx + E;

  // ---- workspace layout ----
  u32* row_ptr = (u32*)d_ws;                             // M+1
  u32* packed  = row_ptr + M + 1;                        // E
  size_t u32B  = ((M + 1 + (size_t)E) * 4 + 15) / 16 * 16;
  float* Wbuf  = (float*)((char*)d_ws + u32B);           // R*DD*DD
  float* A     = Wbuf + (size_t)R * DD * DD;             // N*DD intermediate
  u32* cnt     = (u32*)(A + (size_t)N * DD);             // M (build phase only)
  u32* fill    = cnt + M;                                // M
  u32* partials= fill + M;                               // <=1024

  const int NB_SCAN = (int)((M + 1023) / 1024);
  const int NB3     = (int)((M + 1 + 1023) / 1024);
  const int nb_x    = (N + DD - 1) / DD;
  const int nb_e    = (E + 255) / 256;

  // ---- build bucket CSR (once; edges constant across layers) ----
  zero_u32_kernel<<<(int)((2 * M + 255) / 256), 256, 0, stream>>>(cnt, (int)(2 * M));
  hist_kernel<<<nb_e, 256, 0, stream>>>(edst, etyp, cnt, E, R);
  scan1_kernel<<<NB_SCAN, 1024, 0, stream>>>(cnt, row_ptr, partials, (int)M);
  scan2_kernel<<<1, 1024, 0, stream>>>(partials, NB_SCAN);
  scan3_kernel<<<NB3, 1024, 0, stream>>>(row_ptr, partials, (int)M, E);
  scatter_kernel<<<nb_e, 256, 0, stream>>>(esrc, edst, etyp, row_ptr, fill, packed, E, R);

  // ---- layers ----
  for (int l = 0; l < L; ++l) {
    const float* xin = (l == 0) ? x0 : A;
    float* outf      = (l == L - 1) ? (float*)d_out : A;

    compute_w_kernel<<<(R * DD * DD + 255) / 256, 256, 0, stream>>>(
        basis + (size_t)l * Bn * DD * DD, coeff + (size_t)l * R * Bn, Wbuf, R, Bn);

    fused_layer_kernel<<<nb_x, 256, 0, stream>>>(
        xin, packed, row_ptr, Wbuf, self_w + (size_t)l * DD * DD,
        bias + (size_t)l * DD, outf, N, R);
  }
}

// Round 6
// 617.583 us; speedup vs baseline: 1.6004x; 1.5018x over previous
//
#include <hip/hip_runtime.h>
#include <hip/hip_bf16.h>

#define DD 64
#define XPAD 68   // padded leading dim for transposed LDS tile

typedef unsigned int u32;

__device__ __forceinline__ float bf2f(unsigned short u) {
  union { u32 i; float f; } c;
  c.i = ((u32)u) << 16;
  return c.f;
}

// ---------------- preprocessing: CSR by destination ----------------

__global__ __launch_bounds__(256) void zero_u32_kernel(u32* __restrict__ p, int n) {
  int i = blockIdx.x * 256 + threadIdx.x;
  if (i < n) p[i] = 0u;
}

__global__ __launch_bounds__(256) void hist_kernel(const int* __restrict__ edst,
                                                   u32* __restrict__ cnt, int E) {
  int e = blockIdx.x * 256 + threadIdx.x;
  if (e < E) atomicAdd(&cnt[edst[e]], 1u);
}

__global__ __launch_bounds__(1024) void scan1_kernel(const u32* __restrict__ cnt,
                                                     u32* __restrict__ row_ptr,
                                                     u32* __restrict__ partials, int M) {
  __shared__ u32 s[1024];
  int t = threadIdx.x;
  int gid = blockIdx.x * 1024 + t;
  u32 v = (gid < M) ? cnt[gid] : 0u;
  s[t] = v;
  __syncthreads();
  for (int off = 1; off < 1024; off <<= 1) {
    u32 x = (t >= off) ? s[t - off] : 0u;
    __syncthreads();
    s[t] += x;
    __syncthreads();
  }
  if (gid < M) row_ptr[gid] = s[t] - v;          // exclusive within block
  if (t == 1023) partials[blockIdx.x] = s[1023]; // block total
}

__global__ __launch_bounds__(1024) void scan2_kernel(u32* __restrict__ partials, int nb) {
  __shared__ u32 s[1024];
  int t = threadIdx.x;
  u32 v = (t < nb) ? partials[t] : 0u;
  s[t] = v;
  __syncthreads();
  for (int off = 1; off < 1024; off <<= 1) {
    u32 x = (t >= off) ? s[t - off] : 0u;
    __syncthreads();
    s[t] += x;
    __syncthreads();
  }
  if (t < nb) partials[t] = s[t] - v;            // exclusive
}

__global__ __launch_bounds__(1024) void scan3_kernel(u32* __restrict__ row_ptr,
                                                     const u32* __restrict__ partials,
                                                     int M, int E) {
  int gid = blockIdx.x * 1024 + threadIdx.x;
  if (gid < M) row_ptr[gid] += partials[blockIdx.x];
  else if (gid == M) row_ptr[M] = (u32)E;
}

// packed[pos] = src | ty << sh
__global__ __launch_bounds__(256) void scatter_kernel(const int* __restrict__ esrc,
                                                      const int* __restrict__ edst,
                                                      const int* __restrict__ et,
                                                      const u32* __restrict__ row_ptr,
                                                      u32* __restrict__ fill,
                                                      u32* __restrict__ packed,
                                                      int E, int sh) {
  int e = blockIdx.x * 256 + threadIdx.x;
  if (e >= E) return;
  int d = edst[e];
  u32 pos = row_ptr[d] + atomicAdd(&fill[d], 1u);
  packed[pos] = (u32)esrc[e] | ((u32)et[e] << sh);
}

// ---------------- per-layer compute ----------------

// W[r,i,o] = sum_b coeff[r,b] * basis[b,i,o]
__global__ __launch_bounds__(256) void compute_w_kernel(
    const float* __restrict__ basis, const float* __restrict__ coeff,
    float* __restrict__ W, int Rn, int Bn) {
  int idx = blockIdx.x * 256 + threadIdx.x;
  if (idx >= Rn * DD * DD) return;
  int r = idx / (DD * DD);
  int io = idx - r * DD * DD;
  float acc = 0.f;
  for (int b = 0; b < Bn; ++b)
    acc += coeff[r * Bn + b] * basis[b * DD * DD + io];
  W[idx] = acc;
}

// h16[m][n][o] = (x @ W_m)[n][o]  for m<R;  h16[R][n][o] = (x @ self_w + bias)[n][o]
// One block = 64-node tile; x tile staged once, W swapped per m.
__global__ __launch_bounds__(256) void transform_h_kernel(
    const float* __restrict__ x, const float* __restrict__ W,
    const float* __restrict__ self_w, const float* __restrict__ bias_l,
    unsigned short* __restrict__ h16, int N, int R) {
  __shared__ __align__(16) float Ws[DD * DD];
  __shared__ __align__(16) float xsT[DD * XPAD];   // [feature][node_local]

  const int t = threadIdx.x;
  const int nbase = blockIdx.x * DD;

  // stage transposed x tile once
  for (int j = t; j < DD * DD; j += 256) {
    int nl = j >> 6;
    int i  = j & 63;
    int n  = nbase + nl;
    xsT[i * XPAD + nl] = (n < N) ? x[(size_t)n * DD + i] : 0.f;
  }

  const int o0 = (t & 15) * 4;
  const int n0 = (t >> 4) * 4;
  float4 bv = *reinterpret_cast<const float4*>(&bias_l[o0]);

  for (int m = 0; m <= R; ++m) {
    if (m) __syncthreads();   // all waves done with previous Ws
    const float* Wsrc = (m == R) ? self_w : (W + (size_t)m * DD * DD);
    for (int j = t; j < DD * DD; j += 256) Ws[j] = Wsrc[j];
    __syncthreads();          // Ws (and xsT on m==0) ready

    float acc[4][4];
#pragma unroll
    for (int a = 0; a < 4; ++a)
#pragma unroll
      for (int b = 0; b < 4; ++b) acc[a][b] = 0.f;

#pragma unroll 4
    for (int i = 0; i < DD; ++i) {
      float4 wv = *reinterpret_cast<const float4*>(&Ws[i * DD + o0]);
      float4 xv = *reinterpret_cast<const float4*>(&xsT[i * XPAD + n0]);
      float xa[4] = {xv.x, xv.y, xv.z, xv.w};
      float wa[4] = {wv.x, wv.y, wv.z, wv.w};
#pragma unroll
      for (int a = 0; a < 4; ++a)
#pragma unroll
        for (int b = 0; b < 4; ++b) acc[a][b] += xa[a] * wa[b];
    }

    const bool self = (m == R);
#pragma unroll
    for (int a = 0; a < 4; ++a) {
      int n = nbase + n0 + a;
      if (n < N) {
        float v0 = acc[a][0], v1 = acc[a][1], v2 = acc[a][2], v3 = acc[a][3];
        if (self) { v0 += bv.x; v1 += bv.y; v2 += bv.z; v3 += bv.w; }
        __hip_bfloat16 b0 = __float2bfloat16(v0);
        __hip_bfloat16 b1 = __float2bfloat16(v1);
        __hip_bfloat16 b2 = __float2bfloat16(v2);
        __hip_bfloat16 b3 = __float2bfloat16(v3);
        ushort4 o;
        o.x = *reinterpret_cast<unsigned short*>(&b0);
        o.y = *reinterpret_cast<unsigned short*>(&b1);
        o.z = *reinterpret_cast<unsigned short*>(&b2);
        o.w = *reinterpret_cast<unsigned short*>(&b3);
        *reinterpret_cast<ushort4*>(
            &h16[(((size_t)m * N + n) << 6) + o0]) = o;
      }
    }
  }
}

// One wave per destination node; lane = feature.
// out[n] = relu(h16[R][n] + sum_edges h16[ty][src])
__global__ __launch_bounds__(256) void aggregate_out_kernel(
    const u32* __restrict__ packed, const u32* __restrict__ row_ptr,
    const unsigned short* __restrict__ h16, float* __restrict__ out,
    int N, int R, int sh) {
  int wid  = (blockIdx.x * 256 + threadIdx.x) >> 6;
  int lane = threadIdx.x & 63;
  if (wid >= N) return;
  const u32 mask = (1u << sh) - 1u;
  u32 beg = row_ptr[wid], end = row_ptr[wid + 1];

  float s0 = bf2f(h16[(((size_t)R * N + wid) << 6) + lane]);  // self + bias
  float s1 = 0.f, s2 = 0.f, s3 = 0.f;
  u32 e = beg;
  for (; e + 4 <= end; e += 4) {
    u32 p0 = packed[e], p1 = packed[e + 1], p2 = packed[e + 2], p3 = packed[e + 3];
    s0 += bf2f(h16[(((size_t)(p0 >> sh) * N + (p0 & mask)) << 6) + lane]);
    s1 += bf2f(h16[(((size_t)(p1 >> sh) * N + (p1 & mask)) << 6) + lane]);
    s2 += bf2f(h16[(((size_t)(p2 >> sh) * N + (p2 & mask)) << 6) + lane]);
    s3 += bf2f(h16[(((size_t)(p3 >> sh) * N + (p3 & mask)) << 6) + lane]);
  }
  for (; e < end; ++e) {
    u32 p = packed[e];
    s0 += bf2f(h16[(((size_t)(p >> sh) * N + (p & mask)) << 6) + lane]);
  }
  float sum = (s0 + s1) + (s2 + s3);
  out[((size_t)wid << 6) + lane] = fmaxf(sum, 0.f);
}

extern "C" void kernel_launch(void* const* d_in, const int* in_sizes, int n_in,
                              void* d_out, int out_size, void* d_ws, size_t ws_size,
                              hipStream_t stream) {
  const float* x0     = (const float*)d_in[0];
  const float* basis  = (const float*)d_in[1];
  const float* coeff  = (const float*)d_in[2];
  const float* self_w = (const float*)d_in[3];
  const float* bias   = (const float*)d_in[4];
  const int*   eidx   = (const int*)d_in[5];
  const int*   etyp   = (const int*)d_in[6];

  const int N  = in_sizes[0] / DD;
  const int L  = in_sizes[4] / DD;
  const int Bn = in_sizes[1] / (L * DD * DD);
  const int R  = in_sizes[2] / (L * Bn);
  const int E  = in_sizes[6];

  int sh = 0;
  while ((1 << sh) < N) ++sh;     // bits for src id

  const int* esrc = eidx;
  const int* edst = eidx + E;

  // ---- workspace layout ----
  u32* row_ptr = (u32*)d_ws;                               // N+1
  u32* packed  = row_ptr + N + 1;                          // E
  size_t u32B  = (((size_t)N + 1 + E) * 4 + 15) / 16 * 16;
  float* Wbuf  = (float*)((char*)d_ws + u32B);             // R*DD*DD
  float* A     = Wbuf + (size_t)R * DD * DD;               // N*DD fp32 intermediate
  unsigned short* h16 = (unsigned short*)(A + (size_t)N * DD); // (R+1)*N*DD bf16
  // build-phase overlays (h16 region unused until layers)
  u32* cnt      = (u32*)h16;                               // N
  u32* fill     = cnt + N;                                 // N
  u32* partials = fill + N;                                // <=1024

  const int NB_SCAN = (N + 1023) / 1024;
  const int NB3     = (N + 1 + 1023) / 1024;
  const int nb_x    = (N + DD - 1) / DD;
  const int nb_e    = (E + 255) / 256;
  const int nb_agg  = (int)(((size_t)N * 64 + 255) / 256);

  // ---- build CSR (once; edges constant across layers) ----
  zero_u32_kernel<<<(2 * N + 255) / 256, 256, 0, stream>>>(cnt, 2 * N);
  hist_kernel<<<nb_e, 256, 0, stream>>>(edst, cnt, E);
  scan1_kernel<<<NB_SCAN, 1024, 0, stream>>>(cnt, row_ptr, partials, N);
  scan2_kernel<<<1, 1024, 0, stream>>>(partials, NB_SCAN);
  scan3_kernel<<<NB3, 1024, 0, stream>>>(row_ptr, partials, N, E);
  scatter_kernel<<<nb_e, 256, 0, stream>>>(esrc, edst, etyp, row_ptr, fill, packed, E, sh);

  // ---- layers ----
  for (int l = 0; l < L; ++l) {
    const float* xin = (l == 0) ? x0 : A;
    float* outf      = (l == L - 1) ? (float*)d_out : A;

    compute_w_kernel<<<(R * DD * DD + 255) / 256, 256, 0, stream>>>(
        basis + (size_t)l * Bn * DD * DD, coeff + (size_t)l * R * Bn, Wbuf, R, Bn);

    transform_h_kernel<<<nb_x, 256, 0, stream>>>(
        xin, Wbuf, self_w + (size_t)l * DD * DD, bias + (size_t)l * DD, h16, N, R);

    aggregate_out_kernel<<<nb_agg, 256, 0, stream>>>(
        packed, row_ptr, h16, outf, N, R, sh);
  }
}

// Round 7
// 537.676 us; speedup vs baseline: 1.8383x; 1.1486x over previous
//
#include <hip/hip_runtime.h>
#include <hip/hip_bf16.h>

#define DD 64

typedef unsigned int u32;
typedef __attribute__((ext_vector_type(8))) short bf16x8;
typedef __attribute__((ext_vector_type(4))) float f32x4;

__device__ __forceinline__ float bf2f(unsigned short u) {
  union { u32 i; float f; } c;
  c.i = ((u32)u) << 16;
  return c.f;
}
__device__ __forceinline__ unsigned short f2bf(float f) {
  __hip_bfloat16 h = __float2bfloat16(f);
  return *reinterpret_cast<unsigned short*>(&h);
}

// ---------------- preprocessing: CSR by destination ----------------

__global__ __launch_bounds__(256) void zero_u32_kernel(u32* __restrict__ p, int n) {
  int i = blockIdx.x * 256 + threadIdx.x;
  if (i < n) p[i] = 0u;
}

__global__ __launch_bounds__(256) void hist_kernel(const int* __restrict__ edst,
                                                   u32* __restrict__ cnt, int E) {
  int e = blockIdx.x * 256 + threadIdx.x;
  if (e < E) atomicAdd(&cnt[edst[e]], 1u);
}

__global__ __launch_bounds__(1024) void scan1_kernel(const u32* __restrict__ cnt,
                                                     u32* __restrict__ row_ptr,
                                                     u32* __restrict__ partials, int M) {
  __shared__ u32 s[1024];
  int t = threadIdx.x;
  int gid = blockIdx.x * 1024 + t;
  u32 v = (gid < M) ? cnt[gid] : 0u;
  s[t] = v;
  __syncthreads();
  for (int off = 1; off < 1024; off <<= 1) {
    u32 x = (t >= off) ? s[t - off] : 0u;
    __syncthreads();
    s[t] += x;
    __syncthreads();
  }
  if (gid < M) row_ptr[gid] = s[t] - v;          // exclusive within block
  if (t == 1023) partials[blockIdx.x] = s[1023]; // block total
}

__global__ __launch_bounds__(1024) void scan2_kernel(u32* __restrict__ partials, int nb) {
  __shared__ u32 s[1024];
  int t = threadIdx.x;
  u32 v = (t < nb) ? partials[t] : 0u;
  s[t] = v;
  __syncthreads();
  for (int off = 1; off < 1024; off <<= 1) {
    u32 x = (t >= off) ? s[t - off] : 0u;
    __syncthreads();
    s[t] += x;
    __syncthreads();
  }
  if (t < nb) partials[t] = s[t] - v;            // exclusive
}

__global__ __launch_bounds__(1024) void scan3_kernel(u32* __restrict__ row_ptr,
                                                     const u32* __restrict__ partials,
                                                     int M, int E) {
  int gid = blockIdx.x * 1024 + threadIdx.x;
  if (gid < M) row_ptr[gid] += partials[blockIdx.x];
  else if (gid == M) row_ptr[M] = (u32)E;
}

// packed[pos] = src | ty << sh
__global__ __launch_bounds__(256) void scatter_kernel(const int* __restrict__ esrc,
                                                      const int* __restrict__ edst,
                                                      const int* __restrict__ et,
                                                      const u32* __restrict__ row_ptr,
                                                      u32* __restrict__ fill,
                                                      u32* __restrict__ packed,
                                                      int E, int sh) {
  int e = blockIdx.x * 256 + threadIdx.x;
  if (e >= E) return;
  int d = edst[e];
  u32 pos = row_ptr[d] + atomicAdd(&fill[d], 1u);
  packed[pos] = (u32)esrc[e] | ((u32)et[e] << sh);
}

// ---------------- per-layer compute ----------------

// Wt16[m][o][k] = bf16( sum_b coeff[m,b]*basis[b,k,o] ) for m<R; self_w[k,o] for m==R.
__global__ __launch_bounds__(256) void compute_wt_kernel(
    const float* __restrict__ basis, const float* __restrict__ coeff,
    const float* __restrict__ self_w, unsigned short* __restrict__ Wt16,
    int R, int Bn) {
  int idx = blockIdx.x * 256 + threadIdx.x;
  int total = (R + 1) * DD * DD;
  if (idx >= total) return;
  int m = idx >> 12;          // / (DD*DD)
  int k = (idx >> 6) & 63;
  int o = idx & 63;           // contiguous -> coalesced basis reads
  float acc = 0.f;
  if (m == R) {
    acc = self_w[k * DD + o];
  } else {
    for (int b = 0; b < Bn; ++b)
      acc += coeff[m * Bn + b] * basis[((size_t)b * DD + k) * DD + o];
  }
  Wt16[((size_t)m * DD + o) * DD + k] = f2bf(acc);
}

// h16[m][n][o] = bf16( (x @ W_m)[n][o] )  (m==R: x @ self_w, no bias)
// Block = 64-node tile, 4 waves x 16 rows. MFMA 16x16x32 bf16, zero LDS.
// A-frag layout: row=lane&15, k=(lane>>4)*8+e. B: col=lane&15, k=(lane>>4)*8+e.
// C/D: col=lane&15, row=(lane>>4)*4+reg  [m89-verified].
__global__ __launch_bounds__(256) void transform_h_kernel(
    const float* __restrict__ x, const unsigned short* __restrict__ Wt16,
    unsigned short* __restrict__ h16, int N, int R) {
  const int t    = threadIdx.x;
  const int w    = t >> 6;
  const int lane = t & 63;
  const int l16  = lane & 15;
  const int kg   = lane >> 4;               // 0..3
  const int rowbase = blockIdx.x * DD + w * 16;
  const int arow = rowbase + l16;

  // A fragments from x (fp32 -> bf16), loaded once, reused for all 9 matrices
  bf16x8 Afrag[2];
  {
    const bool ok = (arow < N);
    const float* xp = x + (size_t)arow * DD + kg * 8;
#pragma unroll
    for (int kc = 0; kc < 2; ++kc) {
      float4 v0 = ok ? *reinterpret_cast<const float4*>(xp + kc * 32)
                     : make_float4(0.f, 0.f, 0.f, 0.f);
      float4 v1 = ok ? *reinterpret_cast<const float4*>(xp + kc * 32 + 4)
                     : make_float4(0.f, 0.f, 0.f, 0.f);
      bf16x8 a;
      a[0] = (short)f2bf(v0.x); a[1] = (short)f2bf(v0.y);
      a[2] = (short)f2bf(v0.z); a[3] = (short)f2bf(v0.w);
      a[4] = (short)f2bf(v1.x); a[5] = (short)f2bf(v1.y);
      a[6] = (short)f2bf(v1.z); a[7] = (short)f2bf(v1.w);
      Afrag[kc] = a;
    }
  }

  const int orow0 = rowbase + kg * 4;       // first C/D row this lane owns

  for (int m = 0; m <= R; ++m) {
    const unsigned short* wb = Wt16 + (size_t)m * DD * DD;
    f32x4 acc[4];
#pragma unroll
    for (int t4 = 0; t4 < 4; ++t4) {
      acc[t4][0] = 0.f; acc[t4][1] = 0.f; acc[t4][2] = 0.f; acc[t4][3] = 0.f;
      const unsigned short* bp = wb + ((size_t)(t4 * 16 + l16)) * DD + kg * 8;
      bf16x8 B0 = *reinterpret_cast<const bf16x8*>(bp);        // k 0..31 slice
      bf16x8 B1 = *reinterpret_cast<const bf16x8*>(bp + 32);   // k 32..63 slice
      acc[t4] = __builtin_amdgcn_mfma_f32_16x16x32_bf16(Afrag[0], B0, acc[t4], 0, 0, 0);
      acc[t4] = __builtin_amdgcn_mfma_f32_16x16x32_bf16(Afrag[1], B1, acc[t4], 0, 0, 0);
    }
    unsigned short* hp = h16 + (size_t)m * N * DD;
#pragma unroll
    for (int t4 = 0; t4 < 4; ++t4) {
#pragma unroll
      for (int r = 0; r < 4; ++r) {
        int row = orow0 + r;
        if (row < N)
          hp[(size_t)row * DD + t4 * 16 + l16] = f2bf(acc[t4][r]);
      }
    }
  }
}

// One wave per destination node; lane = feature.
// out[n] = relu(bias[lane] + h16[R][n] + sum_edges h16[ty][src])
__global__ __launch_bounds__(256) void aggregate_out_kernel(
    const u32* __restrict__ packed, const u32* __restrict__ row_ptr,
    const unsigned short* __restrict__ h16, const float* __restrict__ bias_l,
    float* __restrict__ out, int N, int R, int sh) {
  int wid  = (blockIdx.x * 256 + threadIdx.x) >> 6;
  int lane = threadIdx.x & 63;
  if (wid >= N) return;
  const u32 mask = (1u << sh) - 1u;
  u32 beg = row_ptr[wid], end = row_ptr[wid + 1];

  float s0 = bias_l[lane] + bf2f(h16[(((size_t)R * N + wid) << 6) + lane]);  // self
  float s1 = 0.f, s2 = 0.f, s3 = 0.f;
  u32 e = beg;
  for (; e + 4 <= end; e += 4) {
    u32 p0 = packed[e], p1 = packed[e + 1], p2 = packed[e + 2], p3 = packed[e + 3];
    s0 += bf2f(h16[(((size_t)(p0 >> sh) * N + (p0 & mask)) << 6) + lane]);
    s1 += bf2f(h16[(((size_t)(p1 >> sh) * N + (p1 & mask)) << 6) + lane]);
    s2 += bf2f(h16[(((size_t)(p2 >> sh) * N + (p2 & mask)) << 6) + lane]);
    s3 += bf2f(h16[(((size_t)(p3 >> sh) * N + (p3 & mask)) << 6) + lane]);
  }
  for (; e < end; ++e) {
    u32 p = packed[e];
    s0 += bf2f(h16[(((size_t)(p >> sh) * N + (p & mask)) << 6) + lane]);
  }
  float sum = (s0 + s1) + (s2 + s3);
  out[((size_t)wid << 6) + lane] = fmaxf(sum, 0.f);
}

extern "C" void kernel_launch(void* const* d_in, const int* in_sizes, int n_in,
                              void* d_out, int out_size, void* d_ws, size_t ws_size,
                              hipStream_t stream) {
  const float* x0     = (const float*)d_in[0];
  const float* basis  = (const float*)d_in[1];
  const float* coeff  = (const float*)d_in[2];
  const float* self_w = (const float*)d_in[3];
  const float* bias   = (const float*)d_in[4];
  const int*   eidx   = (const int*)d_in[5];
  const int*   etyp   = (const int*)d_in[6];

  const int N  = in_sizes[0] / DD;
  const int L  = in_sizes[4] / DD;
  const int Bn = in_sizes[1] / (L * DD * DD);
  const int R  = in_sizes[2] / (L * Bn);
  const int E  = in_sizes[6];

  int sh = 0;
  while ((1 << sh) < N) ++sh;     // bits for src id

  const int* esrc = eidx;
  const int* edst = eidx + E;

  // ---- workspace layout ----
  u32* row_ptr = (u32*)d_ws;                               // N+1
  u32* packed  = row_ptr + N + 1;                          // E
  size_t u32B  = (((size_t)N + 1 + E) * 4 + 15) / 16 * 16;
  unsigned short* Wt16 = (unsigned short*)((char*)d_ws + u32B);   // (R+1)*DD*DD bf16
  size_t wtB   = (u32B + (size_t)(R + 1) * DD * DD * 2 + 15) / 16 * 16;
  float* A     = (float*)((char*)d_ws + wtB);              // N*DD fp32 intermediate
  unsigned short* h16 = (unsigned short*)(A + (size_t)N * DD);    // (R+1)*N*DD bf16
  // build-phase overlays (h16 region unused until layers)
  u32* cnt      = (u32*)h16;                               // N
  u32* fill     = cnt + N;                                 // N
  u32* partials = fill + N;                                // <=1024

  const int NB_SCAN = (N + 1023) / 1024;
  const int NB3     = (N + 1 + 1023) / 1024;
  const int nb_x    = (N + DD - 1) / DD;
  const int nb_e    = (E + 255) / 256;
  const int nb_agg  = (int)(((size_t)N * 64 + 255) / 256);
  const int nb_wt   = ((R + 1) * DD * DD + 255) / 256;

  // ---- build CSR (once; edges constant across layers) ----
  zero_u32_kernel<<<(2 * N + 255) / 256, 256, 0, stream>>>(cnt, 2 * N);
  hist_kernel<<<nb_e, 256, 0, stream>>>(edst, cnt, E);
  scan1_kernel<<<NB_SCAN, 1024, 0, stream>>>(cnt, row_ptr, partials, N);
  scan2_kernel<<<1, 1024, 0, stream>>>(partials, NB_SCAN);
  scan3_kernel<<<NB3, 1024, 0, stream>>>(row_ptr, partials, N, E);
  scatter_kernel<<<nb_e, 256, 0, stream>>>(esrc, edst, etyp, row_ptr, fill, packed, E, sh);

  // ---- layers ----
  for (int l = 0; l < L; ++l) {
    const float* xin = (l == 0) ? x0 : A;
    float* outf      = (l == L - 1) ? (float*)d_out : A;

    compute_wt_kernel<<<nb_wt, 256, 0, stream>>>(
        basis + (size_t)l * Bn * DD * DD, coeff + (size_t)l * R * Bn,
        self_w + (size_t)l * DD * DD, Wt16, R, Bn);

    transform_h_kernel<<<nb_x, 256, 0, stream>>>(xin, Wt16, h16, N, R);

    aggregate_out_kernel<<<nb_agg, 256, 0, stream>>>(
        packed, row_ptr, h16, bias + (size_t)l * DD, outf, N, R, sh);
  }
}

// Round 8
// 447.299 us; speedup vs baseline: 2.2097x; 1.2021x over previous
//
#include <hip/hip_runtime.h>
#include <hip/hip_bf16.h>

#define DD 64
#define EPB 4096   // edges per binscatter block (16 per thread)

typedef unsigned int u32;
typedef __attribute__((ext_vector_type(8))) short bf16x8;
typedef __attribute__((ext_vector_type(4))) float f32x4;

__device__ __forceinline__ float bf2f(unsigned short u) {
  union { u32 i; float f; } c;
  c.i = ((u32)u) << 16;
  return c.f;
}
__device__ __forceinline__ unsigned short f2bf(float f) {
  __hip_bfloat16 h = __float2bfloat16(f);
  return *reinterpret_cast<unsigned short*>(&h);
}

// ---------------- preprocessing: two-level binned CSR build ----------------

__global__ __launch_bounds__(256) void zero_u32_kernel(u32* __restrict__ p, int n) {
  int i = blockIdx.x * 256 + threadIdx.x;
  if (i < n) p[i] = 0u;
}

// LDS-aggregated histogram of coarse bins (dst >> sh_bin).
__global__ __launch_bounds__(256) void coarse_hist_kernel(
    const int* __restrict__ edst, u32* __restrict__ ccnt,
    int E, int sh_bin, int nbins) {
  __shared__ u32 lh[1024];
  const int t = threadIdx.x;
  for (int j = t; j < nbins; j += 256) lh[j] = 0u;
  __syncthreads();
  for (int e = blockIdx.x * 256 + t; e < E; e += gridDim.x * 256)
    atomicAdd(&lh[edst[e] >> sh_bin], 1u);
  __syncthreads();
  for (int j = t; j < nbins; j += 256) {
    u32 c = lh[j];
    if (c) atomicAdd(&ccnt[j], c);
  }
}

// Single-block exclusive scan of bin counts -> bin_base (+ cursor copy).
__global__ __launch_bounds__(1024) void coarse_scan_kernel(
    const u32* __restrict__ ccnt, u32* __restrict__ bin_base,
    u32* __restrict__ bin_cursor, int nbins, int E) {
  __shared__ u32 s[1024];
  const int t = threadIdx.x;
  u32 v = (t < nbins) ? ccnt[t] : 0u;
  s[t] = v;
  __syncthreads();
  for (int off = 1; off < 1024; off <<= 1) {
    u32 x = (t >= off) ? s[t - off] : 0u;
    __syncthreads();
    s[t] += x;
    __syncthreads();
  }
  if (t < nbins) {
    u32 ex = s[t] - v;
    bin_base[t] = ex;
    bin_cursor[t] = ex;
  }
  if (t == 0) bin_base[nbins] = (u32)E;
}

// Per-block LDS multisplit into coarse bins; one global atomic per (block,bin).
// tmp runs are written contiguously per bin -> coalesced.
__global__ __launch_bounds__(256) void binscatter_kernel(
    const int* __restrict__ esrc, const int* __restrict__ edst,
    const int* __restrict__ et, u32* __restrict__ bin_cursor,
    u32* __restrict__ tmp_sr, u32* __restrict__ tmp_d,
    int E, int sh_bin, int sh, int nbins) {
  __shared__ u32 lhist[1024];
  __shared__ u32 lbase[1024];
  const int t = threadIdx.x;
  const int base = blockIdx.x * EPB;
  for (int j = t; j < nbins; j += 256) lhist[j] = 0u;
  __syncthreads();
  u32 br[16];
#pragma unroll
  for (int k = 0; k < 16; ++k) {
    int e = base + k * 256 + t;
    if (e < E) {
      int bn = edst[e] >> sh_bin;
      u32 r = atomicAdd(&lhist[bn], 1u);
      br[k] = ((u32)bn << 13) | r;           // bn<1024, r<8192
    }
  }
  __syncthreads();
  for (int j = t; j < nbins; j += 256) {
    u32 c = lhist[j];
    lbase[j] = c ? atomicAdd(&bin_cursor[j], c) : 0u;
  }
  __syncthreads();
#pragma unroll
  for (int k = 0; k < 16; ++k) {
    int e = base + k * 256 + t;
    if (e < E) {
      u32 bn = br[k] >> 13, r = br[k] & 0x1FFFu;
      u32 pos = lbase[bn] + r;
      tmp_sr[pos] = (u32)esrc[e] | ((u32)et[e] << sh);
      tmp_d[pos] = (u32)edst[e];
    }
  }
}

// One block per bin: LDS fine hist (<=256 dsts) + LDS scan -> row_ptr slice,
// then scatter into packed (writes land in the bin's ~10KB window; L2-local).
__global__ __launch_bounds__(256) void finescatter_kernel(
    const u32* __restrict__ tmp_sr, const u32* __restrict__ tmp_d,
    const u32* __restrict__ bin_base, u32* __restrict__ row_ptr,
    u32* __restrict__ packed, int N, int E, int sh_bin) {
  __shared__ u32 dcnt[256];
  __shared__ u32 s[256];
  const int t = threadIdx.x;
  const int b = blockIdx.x;
  const u32 beg = bin_base[b], end = bin_base[b + 1];
  const int W  = 1 << sh_bin;                // <= 256
  const int d0 = b << sh_bin;

  if (t < W) dcnt[t] = 0u;
  __syncthreads();
  for (u32 e = beg + t; e < end; e += 256)
    atomicAdd(&dcnt[(int)tmp_d[e] - d0], 1u);
  __syncthreads();
  u32 v = (t < W) ? dcnt[t] : 0u;
  s[t] = v;
  __syncthreads();
  for (int off = 1; off < 256; off <<= 1) {
    u32 x = (t >= off) ? s[t - off] : 0u;
    __syncthreads();
    s[t] += x;
    __syncthreads();
  }
  const u32 ex = s[t] - v;                   // exclusive scan
  if (t < W) {
    int d = d0 + t;
    if (d < N) row_ptr[d] = beg + ex;
    dcnt[t] = beg + ex;                      // cursor
  }
  if (b == 0 && t == 0) row_ptr[N] = (u32)E;
  __syncthreads();
  for (u32 e = beg + t; e < end; e += 256) {
    int dl = (int)tmp_d[e] - d0;
    u32 pos = atomicAdd(&dcnt[dl], 1u);
    packed[pos] = tmp_sr[e];
  }
}

// ---------------- per-layer compute ----------------

// Wt16[m][o][k] = bf16( sum_b coeff[m,b]*basis[b,k,o] ) for m<R; self_w[k,o] for m==R.
__global__ __launch_bounds__(256) void compute_wt_kernel(
    const float* __restrict__ basis, const float* __restrict__ coeff,
    const float* __restrict__ self_w, unsigned short* __restrict__ Wt16,
    int R, int Bn) {
  int idx = blockIdx.x * 256 + threadIdx.x;
  int total = (R + 1) * DD * DD;
  if (idx >= total) return;
  int m = idx >> 12;
  int k = (idx >> 6) & 63;
  int o = idx & 63;
  float acc = 0.f;
  if (m == R) {
    acc = self_w[k * DD + o];
  } else {
    for (int b = 0; b < Bn; ++b)
      acc += coeff[m * Bn + b] * basis[((size_t)b * DD + k) * DD + o];
  }
  Wt16[((size_t)m * DD + o) * DD + k] = f2bf(acc);
}

// h16[m][n][o] = bf16( (x @ W_m)[n][o] )  (m==R: x @ self_w, no bias)
// Block = 64-node tile, 4 waves x 16 rows. MFMA 16x16x32 bf16, zero LDS.
__global__ __launch_bounds__(256) void transform_h_kernel(
    const float* __restrict__ x, const unsigned short* __restrict__ Wt16,
    unsigned short* __restrict__ h16, int N, int R) {
  const int t    = threadIdx.x;
  const int w    = t >> 6;
  const int lane = t & 63;
  const int l16  = lane & 15;
  const int kg   = lane >> 4;
  const int rowbase = blockIdx.x * DD + w * 16;
  const int arow = rowbase + l16;

  bf16x8 Afrag[2];
  {
    const bool ok = (arow < N);
    const float* xp = x + (size_t)arow * DD + kg * 8;
#pragma unroll
    for (int kc = 0; kc < 2; ++kc) {
      float4 v0 = ok ? *reinterpret_cast<const float4*>(xp + kc * 32)
                     : make_float4(0.f, 0.f, 0.f, 0.f);
      float4 v1 = ok ? *reinterpret_cast<const float4*>(xp + kc * 32 + 4)
                     : make_float4(0.f, 0.f, 0.f, 0.f);
      bf16x8 a;
      a[0] = (short)f2bf(v0.x); a[1] = (short)f2bf(v0.y);
      a[2] = (short)f2bf(v0.z); a[3] = (short)f2bf(v0.w);
      a[4] = (short)f2bf(v1.x); a[5] = (short)f2bf(v1.y);
      a[6] = (short)f2bf(v1.z); a[7] = (short)f2bf(v1.w);
      Afrag[kc] = a;
    }
  }

  const int orow0 = rowbase + kg * 4;

  for (int m = 0; m <= R; ++m) {
    const unsigned short* wb = Wt16 + (size_t)m * DD * DD;
    f32x4 acc[4];
#pragma unroll
    for (int t4 = 0; t4 < 4; ++t4) {
      acc[t4][0] = 0.f; acc[t4][1] = 0.f; acc[t4][2] = 0.f; acc[t4][3] = 0.f;
      const unsigned short* bp = wb + ((size_t)(t4 * 16 + l16)) * DD + kg * 8;
      bf16x8 B0 = *reinterpret_cast<const bf16x8*>(bp);
      bf16x8 B1 = *reinterpret_cast<const bf16x8*>(bp + 32);
      acc[t4] = __builtin_amdgcn_mfma_f32_16x16x32_bf16(Afrag[0], B0, acc[t4], 0, 0, 0);
      acc[t4] = __builtin_amdgcn_mfma_f32_16x16x32_bf16(Afrag[1], B1, acc[t4], 0, 0, 0);
    }
    unsigned short* hp = h16 + (size_t)m * N * DD;
#pragma unroll
    for (int t4 = 0; t4 < 4; ++t4) {
#pragma unroll
      for (int r = 0; r < 4; ++r) {
        int row = orow0 + r;
        if (row < N)
          hp[(size_t)row * DD + t4 * 16 + l16] = f2bf(acc[t4][r]);
      }
    }
  }
}

// One wave per destination node; lane = feature.
// out[n] = relu(bias[lane] + h16[R][n] + sum_edges h16[ty][src])
__global__ __launch_bounds__(256) void aggregate_out_kernel(
    const u32* __restrict__ packed, const u32* __restrict__ row_ptr,
    const unsigned short* __restrict__ h16, const float* __restrict__ bias_l,
    float* __restrict__ out, int N, int R, int sh) {
  int wid  = (blockIdx.x * 256 + threadIdx.x) >> 6;
  int lane = threadIdx.x & 63;
  if (wid >= N) return;
  const u32 mask = (1u << sh) - 1u;
  u32 beg = row_ptr[wid], end = row_ptr[wid + 1];

  float s0 = bias_l[lane] + bf2f(h16[(((size_t)R * N + wid) << 6) + lane]);
  float s1 = 0.f, s2 = 0.f, s3 = 0.f;
  u32 e = beg;
  for (; e + 4 <= end; e += 4) {
    u32 p0 = packed[e], p1 = packed[e + 1], p2 = packed[e + 2], p3 = packed[e + 3];
    s0 += bf2f(h16[(((size_t)(p0 >> sh) * N + (p0 & mask)) << 6) + lane]);
    s1 += bf2f(h16[(((size_t)(p1 >> sh) * N + (p1 & mask)) << 6) + lane]);
    s2 += bf2f(h16[(((size_t)(p2 >> sh) * N + (p2 & mask)) << 6) + lane]);
    s3 += bf2f(h16[(((size_t)(p3 >> sh) * N + (p3 & mask)) << 6) + lane]);
  }
  for (; e < end; ++e) {
    u32 p = packed[e];
    s0 += bf2f(h16[(((size_t)(p >> sh) * N + (p & mask)) << 6) + lane]);
  }
  float sum = (s0 + s1) + (s2 + s3);
  out[((size_t)wid << 6) + lane] = fmaxf(sum, 0.f);
}

extern "C" void kernel_launch(void* const* d_in, const int* in_sizes, int n_in,
                              void* d_out, int out_size, void* d_ws, size_t ws_size,
                              hipStream_t stream) {
  const float* x0     = (const float*)d_in[0];
  const float* basis  = (const float*)d_in[1];
  const float* coeff  = (const float*)d_in[2];
  const float* self_w = (const float*)d_in[3];
  const float* bias   = (const float*)d_in[4];
  const int*   eidx   = (const int*)d_in[5];
  const int*   etyp   = (const int*)d_in[6];

  const int N  = in_sizes[0] / DD;
  const int L  = in_sizes[4] / DD;
  const int Bn = in_sizes[1] / (L * DD * DD);
  const int R  = in_sizes[2] / (L * Bn);
  const int E  = in_sizes[6];

  int sh = 0;
  while ((1 << sh) < N) ++sh;               // bits for src id (17 at N=100k)
  int sh_bin = 0;
  while ((((N - 1) >> sh_bin) + 1) > 1024) ++sh_bin;   // coarse bin shift (7)
  const int nbins = ((N - 1) >> sh_bin) + 1;           // <= 1024 (782)

  const int* esrc = eidx;
  const int* edst = eidx + E;

  // ---- workspace layout ----
  u32* row_ptr = (u32*)d_ws;                               // N+1
  u32* packed  = row_ptr + N + 1;                          // E
  size_t u32B  = (((size_t)N + 1 + E) * 4 + 15) / 16 * 16;
  unsigned short* Wt16 = (unsigned short*)((char*)d_ws + u32B);   // (R+1)*DD*DD
  size_t wtB   = (u32B + (size_t)(R + 1) * DD * DD * 2 + 15) / 16 * 16;
  float* A     = (float*)((char*)d_ws + wtB);              // N*DD fp32 intermediate
  unsigned short* h16 = (unsigned short*)(A + (size_t)N * DD);    // (R+1)*N*DD bf16
  // build-phase overlays on h16 region
  u32* ccnt       = (u32*)h16;                             // nbins
  u32* bin_base   = ccnt + 1024;                           // nbins+1
  u32* bin_cursor = bin_base + 1025;                       // nbins
  u32* tmp_sr     = bin_cursor + 1024 + 3;                 // E (16B-aligned-ish)
  u32* tmp_d      = tmp_sr + E;                            // E

  const int nb_e   = (E + 255) / 256;
  const int nb_bs  = (E + EPB - 1) / EPB;
  const int nb_agg = (int)(((size_t)N * 64 + 255) / 256);
  const int nb_x   = (N + DD - 1) / DD;
  const int nb_wt  = ((R + 1) * DD * DD + 255) / 256;

  // ---- build CSR (once; edges constant across layers) ----
  zero_u32_kernel<<<(nbins + 255) / 256, 256, 0, stream>>>(ccnt, nbins);
  coarse_hist_kernel<<<1024, 256, 0, stream>>>(edst, ccnt, E, sh_bin, nbins);
  coarse_scan_kernel<<<1, 1024, 0, stream>>>(ccnt, bin_base, bin_cursor, nbins, E);
  binscatter_kernel<<<nb_bs, 256, 0, stream>>>(
      esrc, edst, etyp, bin_cursor, tmp_sr, tmp_d, E, sh_bin, sh, nbins);
  finescatter_kernel<<<nbins, 256, 0, stream>>>(
      tmp_sr, tmp_d, bin_base, row_ptr, packed, N, E, sh_bin);

  // ---- layers ----
  for (int l = 0; l < L; ++l) {
    const float* xin = (l == 0) ? x0 : A;
    float* outf      = (l == L - 1) ? (float*)d_out : A;

    compute_wt_kernel<<<nb_wt, 256, 0, stream>>>(
        basis + (size_t)l * Bn * DD * DD, coeff + (size_t)l * R * Bn,
        self_w + (size_t)l * DD * DD, Wt16, R, Bn);

    transform_h_kernel<<<nb_x, 256, 0, stream>>>(xin, Wt16, h16, N, R);

    aggregate_out_kernel<<<nb_agg, 256, 0, stream>>>(
        packed, row_ptr, h16, bias + (size_t)l * DD, outf, N, R, sh);
  }
}

// Round 9
// 413.191 us; speedup vs baseline: 2.3921x; 1.0825x over previous
//
#include <hip/hip_runtime.h>
#include <hip/hip_bf16.h>

#define DD 64
#define EPB 8192   // edges per binscatter block (32 per thread)

typedef unsigned int u32;
typedef __attribute__((ext_vector_type(8))) short bf16x8;
typedef __attribute__((ext_vector_type(4))) float f32x4;

__device__ __forceinline__ float bf2f(unsigned short u) {
  union { u32 i; float f; } c;
  c.i = ((u32)u) << 16;
  return c.f;
}
__device__ __forceinline__ unsigned short f2bf(float f) {
  __hip_bfloat16 h = __float2bfloat16(f);
  return *reinterpret_cast<unsigned short*>(&h);
}

// ---------------- preprocessing: two-level binned CSR build ----------------
// coarse bins: bn = dst >> sh_bin, nbins <= 256, bin width <= 1024.
// record: src | ty << sh | dlow << (sh+3)   (17+3+10 <= 32 bits)

__global__ __launch_bounds__(256) void zero_u32_kernel(u32* __restrict__ p, int n) {
  int i = blockIdx.x * 256 + threadIdx.x;
  if (i < n) p[i] = 0u;
}

__global__ __launch_bounds__(256) void coarse_hist_kernel(
    const int* __restrict__ edst, u32* __restrict__ ccnt,
    int E, int sh_bin, int nbins) {
  __shared__ u32 lh[256];
  const int t = threadIdx.x;
  for (int j = t; j < nbins; j += 256) lh[j] = 0u;
  __syncthreads();
  for (int e = blockIdx.x * 256 + t; e < E; e += gridDim.x * 256)
    atomicAdd(&lh[edst[e] >> sh_bin], 1u);
  __syncthreads();
  for (int j = t; j < nbins; j += 256) {
    u32 c = lh[j];
    if (c) atomicAdd(&ccnt[j], c);
  }
}

// Single-block exclusive scan of bin counts -> bin_base (+ cursor copy).
__global__ __launch_bounds__(256) void coarse_scan_kernel(
    const u32* __restrict__ ccnt, u32* __restrict__ bin_base,
    u32* __restrict__ bin_cursor, int nbins, int E) {
  __shared__ u32 s[256];
  const int t = threadIdx.x;
  u32 v = (t < nbins) ? ccnt[t] : 0u;
  s[t] = v;
  __syncthreads();
  for (int off = 1; off < 256; off <<= 1) {
    u32 x = (t >= off) ? s[t - off] : 0u;
    __syncthreads();
    s[t] += x;
    __syncthreads();
  }
  if (t < nbins) {
    u32 ex = s[t] - v;
    bin_base[t] = ex;
    bin_cursor[t] = ex;
  }
  if (t == 0) bin_base[nbins] = (u32)E;
}

// Per-block LDS multisplit into coarse bins; one global atomic per (block,bin).
// Runs of ~EPB/nbins contiguous u32 per bin -> near-coalesced writes.
__global__ __launch_bounds__(256) void binscatter_kernel(
    const int* __restrict__ esrc, const int* __restrict__ edst,
    const int* __restrict__ et, u32* __restrict__ bin_cursor,
    u32* __restrict__ tmp, int E, int sh_bin, int sh, int nbins) {
  __shared__ u32 lhist[256];
  __shared__ u32 lbase[256];
  const int t = threadIdx.x;
  const int base = blockIdx.x * EPB;
  for (int j = t; j < nbins; j += 256) lhist[j] = 0u;
  __syncthreads();
  u32 br[32];
#pragma unroll
  for (int k = 0; k < 32; ++k) {
    int e = base + k * 256 + t;
    if (e < E) {
      int bn = edst[e] >> sh_bin;
      u32 r = atomicAdd(&lhist[bn], 1u);
      br[k] = ((u32)bn << 13) | r;           // bn<256, r<8192
    }
  }
  __syncthreads();
  for (int j = t; j < nbins; j += 256) {
    u32 c = lhist[j];
    lbase[j] = c ? atomicAdd(&bin_cursor[j], c) : 0u;
  }
  __syncthreads();
  const u32 wmask = (1u << sh_bin) - 1u;
#pragma unroll
  for (int k = 0; k < 32; ++k) {
    int e = base + k * 256 + t;
    if (e < E) {
      u32 bn = br[k] >> 13, r = br[k] & 0x1FFFu;
      u32 pos = lbase[bn] + r;
      u32 dlow = (u32)edst[e] & wmask;
      tmp[pos] = (u32)esrc[e] | ((u32)et[e] << sh) | (dlow << (sh + 3));
    }
  }
}

// One block per bin: LDS fine hist (<=1024 dsts) + LDS scan -> row_ptr slice,
// then scatter into packed (bin window ~tens of KB; L2-local).
__global__ __launch_bounds__(1024) void finescatter_kernel(
    const u32* __restrict__ tmp, const u32* __restrict__ bin_base,
    u32* __restrict__ row_ptr, u32* __restrict__ packed,
    int N, int E, int sh_bin, int sh) {
  __shared__ u32 dcnt[1024];
  __shared__ u32 s[1024];
  const int t = threadIdx.x;
  const int b = blockIdx.x;
  const u32 beg = bin_base[b], end = bin_base[b + 1];
  const int W  = 1 << sh_bin;                // <= 1024
  const int d0 = b << sh_bin;
  const int dsh = sh + 3;
  const u32 srmask = (1u << dsh) - 1u;

  if (t < W) dcnt[t] = 0u;
  __syncthreads();
  for (u32 e = beg + t; e < end; e += 1024)
    atomicAdd(&dcnt[tmp[e] >> dsh], 1u);
  __syncthreads();
  u32 v = (t < W) ? dcnt[t] : 0u;
  s[t] = v;
  __syncthreads();
  for (int off = 1; off < 1024; off <<= 1) {
    u32 x = (t >= off) ? s[t - off] : 0u;
    __syncthreads();
    s[t] += x;
    __syncthreads();
  }
  const u32 ex = s[t] - v;                   // exclusive scan
  if (t < W) {
    int d = d0 + t;
    if (d < N) row_ptr[d] = beg + ex;
    dcnt[t] = beg + ex;                      // cursor
  }
  if (b == 0 && t == 0) row_ptr[N] = (u32)E;
  __syncthreads();
  for (u32 e = beg + t; e < end; e += 1024) {
    u32 p = tmp[e];
    u32 pos = atomicAdd(&dcnt[p >> dsh], 1u);
    packed[pos] = p & srmask;
  }
}

// ---------------- per-layer compute ----------------

// Wt16[m][o][k] = bf16( sum_b coeff[m,b]*basis[b,k,o] ) for m<R; self_w[k,o] for m==R.
__global__ __launch_bounds__(256) void compute_wt_kernel(
    const float* __restrict__ basis, const float* __restrict__ coeff,
    const float* __restrict__ self_w, unsigned short* __restrict__ Wt16,
    int R, int Bn) {
  int idx = blockIdx.x * 256 + threadIdx.x;
  int total = (R + 1) * DD * DD;
  if (idx >= total) return;
  int m = idx >> 12;
  int k = (idx >> 6) & 63;
  int o = idx & 63;
  float acc = 0.f;
  if (m == R) {
    acc = self_w[k * DD + o];
  } else {
    for (int b = 0; b < Bn; ++b)
      acc += coeff[m * Bn + b] * basis[((size_t)b * DD + k) * DD + o];
  }
  Wt16[((size_t)m * DD + o) * DD + k] = f2bf(acc);
}

// h16[m][n][o] = bf16( (x @ W_m)[n][o] )  (m==R: x @ self_w, no bias)
// Block = 64-node tile, 4 waves x 16 rows. MFMA 16x16x32 bf16, zero LDS.
__global__ __launch_bounds__(256) void transform_h_kernel(
    const float* __restrict__ x, const unsigned short* __restrict__ Wt16,
    unsigned short* __restrict__ h16, int N, int R) {
  const int t    = threadIdx.x;
  const int w    = t >> 6;
  const int lane = t & 63;
  const int l16  = lane & 15;
  const int kg   = lane >> 4;
  const int rowbase = blockIdx.x * DD + w * 16;
  const int arow = rowbase + l16;

  bf16x8 Afrag[2];
  {
    const bool ok = (arow < N);
    const float* xp = x + (size_t)arow * DD + kg * 8;
#pragma unroll
    for (int kc = 0; kc < 2; ++kc) {
      float4 v0 = ok ? *reinterpret_cast<const float4*>(xp + kc * 32)
                     : make_float4(0.f, 0.f, 0.f, 0.f);
      float4 v1 = ok ? *reinterpret_cast<const float4*>(xp + kc * 32 + 4)
                     : make_float4(0.f, 0.f, 0.f, 0.f);
      bf16x8 a;
      a[0] = (short)f2bf(v0.x); a[1] = (short)f2bf(v0.y);
      a[2] = (short)f2bf(v0.z); a[3] = (short)f2bf(v0.w);
      a[4] = (short)f2bf(v1.x); a[5] = (short)f2bf(v1.y);
      a[6] = (short)f2bf(v1.z); a[7] = (short)f2bf(v1.w);
      Afrag[kc] = a;
    }
  }

  const int orow0 = rowbase + kg * 4;

  for (int m = 0; m <= R; ++m) {
    const unsigned short* wb = Wt16 + (size_t)m * DD * DD;
    f32x4 acc[4];
#pragma unroll
    for (int t4 = 0; t4 < 4; ++t4) {
      acc[t4][0] = 0.f; acc[t4][1] = 0.f; acc[t4][2] = 0.f; acc[t4][3] = 0.f;
      const unsigned short* bp = wb + ((size_t)(t4 * 16 + l16)) * DD + kg * 8;
      bf16x8 B0 = *reinterpret_cast<const bf16x8*>(bp);
      bf16x8 B1 = *reinterpret_cast<const bf16x8*>(bp + 32);
      acc[t4] = __builtin_amdgcn_mfma_f32_16x16x32_bf16(Afrag[0], B0, acc[t4], 0, 0, 0);
      acc[t4] = __builtin_amdgcn_mfma_f32_16x16x32_bf16(Afrag[1], B1, acc[t4], 0, 0, 0);
    }
    unsigned short* hp = h16 + (size_t)m * N * DD;
#pragma unroll
    for (int t4 = 0; t4 < 4; ++t4) {
#pragma unroll
      for (int r = 0; r < 4; ++r) {
        int row = orow0 + r;
        if (row < N)
          hp[(size_t)row * DD + t4 * 16 + l16] = f2bf(acc[t4][r]);
      }
    }
  }
}

// One wave per destination node; lane = feature.
// out[n] = relu(bias[lane] + h16[R][n] + sum_edges h16[ty][src])
__global__ __launch_bounds__(256) void aggregate_out_kernel(
    const u32* __restrict__ packed, const u32* __restrict__ row_ptr,
    const unsigned short* __restrict__ h16, const float* __restrict__ bias_l,
    float* __restrict__ out, int N, int R, int sh) {
  int wid  = (blockIdx.x * 256 + threadIdx.x) >> 6;
  int lane = threadIdx.x & 63;
  if (wid >= N) return;
  const u32 mask = (1u << sh) - 1u;
  u32 beg = row_ptr[wid], end = row_ptr[wid + 1];

  float s0 = bias_l[lane] + bf2f(h16[(((size_t)R * N + wid) << 6) + lane]);
  float s1 = 0.f, s2 = 0.f, s3 = 0.f;
  u32 e = beg;
  for (; e + 4 <= end; e += 4) {
    u32 p0 = packed[e], p1 = packed[e + 1], p2 = packed[e + 2], p3 = packed[e + 3];
    s0 += bf2f(h16[(((size_t)(p0 >> sh) * N + (p0 & mask)) << 6) + lane]);
    s1 += bf2f(h16[(((size_t)(p1 >> sh) * N + (p1 & mask)) << 6) + lane]);
    s2 += bf2f(h16[(((size_t)(p2 >> sh) * N + (p2 & mask)) << 6) + lane]);
    s3 += bf2f(h16[(((size_t)(p3 >> sh) * N + (p3 & mask)) << 6) + lane]);
  }
  for (; e < end; ++e) {
    u32 p = packed[e];
    s0 += bf2f(h16[(((size_t)(p >> sh) * N + (p & mask)) << 6) + lane]);
  }
  float sum = (s0 + s1) + (s2 + s3);
  out[((size_t)wid << 6) + lane] = fmaxf(sum, 0.f);
}

extern "C" void kernel_launch(void* const* d_in, const int* in_sizes, int n_in,
                              void* d_out, int out_size, void* d_ws, size_t ws_size,
                              hipStream_t stream) {
  const float* x0     = (const float*)d_in[0];
  const float* basis  = (const float*)d_in[1];
  const float* coeff  = (const float*)d_in[2];
  const float* self_w = (const float*)d_in[3];
  const float* bias   = (const float*)d_in[4];
  const int*   eidx   = (const int*)d_in[5];
  const int*   etyp   = (const int*)d_in[6];

  const int N  = in_sizes[0] / DD;
  const int L  = in_sizes[4] / DD;
  const int Bn = in_sizes[1] / (L * DD * DD);
  const int R  = in_sizes[2] / (L * Bn);
  const int E  = in_sizes[6];

  int sh = 0;
  while ((1 << sh) < N) ++sh;               // src bits (17 at N=100k)
  int sh_bin = 0;
  while ((((N - 1) >> sh_bin) + 1) > 256) ++sh_bin;    // nbins<=256 (sh_bin=9)
  const int nbins = ((N - 1) >> sh_bin) + 1;           // 196 at N=100k

  const int* esrc = eidx;
  const int* edst = eidx + E;

  // ---- workspace layout ----
  u32* row_ptr = (u32*)d_ws;                               // N+1
  u32* packed  = row_ptr + N + 1;                          // E
  size_t u32B  = (((size_t)N + 1 + E) * 4 + 15) / 16 * 16;
  unsigned short* Wt16 = (unsigned short*)((char*)d_ws + u32B);   // (R+1)*DD*DD
  size_t wtB   = (u32B + (size_t)(R + 1) * DD * DD * 2 + 15) / 16 * 16;
  float* A     = (float*)((char*)d_ws + wtB);              // N*DD fp32 intermediate
  unsigned short* h16 = (unsigned short*)(A + (size_t)N * DD);    // (R+1)*N*DD bf16
  // build-phase overlays on h16 region
  u32* ccnt       = (u32*)h16;                             // nbins
  u32* bin_base   = ccnt + 256;                            // nbins+1
  u32* bin_cursor = bin_base + 257;                        // nbins
  u32* tmp        = bin_cursor + 256 + 3;                  // E

  const int nb_bs  = (E + EPB - 1) / EPB;
  const int nb_agg = (int)(((size_t)N * 64 + 255) / 256);
  const int nb_x   = (N + DD - 1) / DD;
  const int nb_wt  = ((R + 1) * DD * DD + 255) / 256;

  // ---- build CSR (once; edges constant across layers) ----
  zero_u32_kernel<<<1, 256, 0, stream>>>(ccnt, nbins);
  coarse_hist_kernel<<<1024, 256, 0, stream>>>(edst, ccnt, E, sh_bin, nbins);
  coarse_scan_kernel<<<1, 256, 0, stream>>>(ccnt, bin_base, bin_cursor, nbins, E);
  binscatter_kernel<<<nb_bs, 256, 0, stream>>>(
      esrc, edst, etyp, bin_cursor, tmp, E, sh_bin, sh, nbins);
  finescatter_kernel<<<nbins, 1024, 0, stream>>>(
      tmp, bin_base, row_ptr, packed, N, E, sh_bin, sh);

  // ---- layers ----
  for (int l = 0; l < L; ++l) {
    const float* xin = (l == 0) ? x0 : A;
    float* outf      = (l == L - 1) ? (float*)d_out : A;

    compute_wt_kernel<<<nb_wt, 256, 0, stream>>>(
        basis + (size_t)l * Bn * DD * DD, coeff + (size_t)l * R * Bn,
        self_w + (size_t)l * DD * DD, Wt16, R, Bn);

    transform_h_kernel<<<nb_x, 256, 0, stream>>>(xin, Wt16, h16, N, R);

    aggregate_out_kernel<<<nb_agg, 256, 0, stream>>>(
        packed, row_ptr, h16, bias + (size_t)l * DD, outf, N, R, sh);
  }
}

// Round 10
// 398.232 us; speedup vs baseline: 2.4820x; 1.0376x over previous
//
#include <hip/hip_runtime.h>
#include <hip/hip_bf16.h>

#define DD 64
#define EPB 8192   // edges per binscatter block (32 per thread)

typedef unsigned int u32;
typedef __attribute__((ext_vector_type(8))) short bf16x8;
typedef __attribute__((ext_vector_type(4))) float f32x4;

__device__ __forceinline__ float bf2f(unsigned short u) {
  union { u32 i; float f; } c;
  c.i = ((u32)u) << 16;
  return c.f;
}
__device__ __forceinline__ unsigned short f2bf(float f) {
  __hip_bfloat16 h = __float2bfloat16(f);
  return *reinterpret_cast<unsigned short*>(&h);
}

// ---------------- preprocessing: two-level binned CSR build ----------------
// coarse bins: bn = dst >> sh_bin, nbins <= 256.
// tmp record: src | ty << sh | dlow << (sh+3)   (17+3+10 <= 32 bits)
// final packed record: rowid = ty*N + src  (direct h16 row index)

__global__ __launch_bounds__(256) void zero_u32_kernel(u32* __restrict__ p, int n) {
  int i = blockIdx.x * 256 + threadIdx.x;
  if (i < n) p[i] = 0u;
}

__global__ __launch_bounds__(256) void coarse_hist_kernel(
    const int* __restrict__ edst, u32* __restrict__ ccnt,
    int E, int sh_bin, int nbins) {
  __shared__ u32 lh[256];
  const int t = threadIdx.x;
  for (int j = t; j < nbins; j += 256) lh[j] = 0u;
  __syncthreads();
  for (int e = blockIdx.x * 256 + t; e < E; e += gridDim.x * 256)
    atomicAdd(&lh[edst[e] >> sh_bin], 1u);
  __syncthreads();
  for (int j = t; j < nbins; j += 256) {
    u32 c = lh[j];
    if (c) atomicAdd(&ccnt[j], c);
  }
}

__global__ __launch_bounds__(256) void coarse_scan_kernel(
    const u32* __restrict__ ccnt, u32* __restrict__ bin_base,
    u32* __restrict__ bin_cursor, int nbins, int E) {
  __shared__ u32 s[256];
  const int t = threadIdx.x;
  u32 v = (t < nbins) ? ccnt[t] : 0u;
  s[t] = v;
  __syncthreads();
  for (int off = 1; off < 256; off <<= 1) {
    u32 x = (t >= off) ? s[t - off] : 0u;
    __syncthreads();
    s[t] += x;
    __syncthreads();
  }
  if (t < nbins) {
    u32 ex = s[t] - v;
    bin_base[t] = ex;
    bin_cursor[t] = ex;
  }
  if (t == 0) bin_base[nbins] = (u32)E;
}

__global__ __launch_bounds__(256) void binscatter_kernel(
    const int* __restrict__ esrc, const int* __restrict__ edst,
    const int* __restrict__ et, u32* __restrict__ bin_cursor,
    u32* __restrict__ tmp, int E, int sh_bin, int sh, int nbins) {
  __shared__ u32 lhist[256];
  __shared__ u32 lbase[256];
  const int t = threadIdx.x;
  const int base = blockIdx.x * EPB;
  for (int j = t; j < nbins; j += 256) lhist[j] = 0u;
  __syncthreads();
  u32 br[32];
#pragma unroll
  for (int k = 0; k < 32; ++k) {
    int e = base + k * 256 + t;
    if (e < E) {
      int bn = edst[e] >> sh_bin;
      u32 r = atomicAdd(&lhist[bn], 1u);
      br[k] = ((u32)bn << 13) | r;           // bn<256, r<8192
    }
  }
  __syncthreads();
  for (int j = t; j < nbins; j += 256) {
    u32 c = lhist[j];
    lbase[j] = c ? atomicAdd(&bin_cursor[j], c) : 0u;
  }
  __syncthreads();
  const u32 wmask = (1u << sh_bin) - 1u;
#pragma unroll
  for (int k = 0; k < 32; ++k) {
    int e = base + k * 256 + t;
    if (e < E) {
      u32 bn = br[k] >> 13, r = br[k] & 0x1FFFu;
      u32 pos = lbase[bn] + r;
      u32 dlow = (u32)edst[e] & wmask;
      tmp[pos] = (u32)esrc[e] | ((u32)et[e] << sh) | (dlow << (sh + 3));
    }
  }
}

// One block per bin: LDS fine hist + scan -> row_ptr slice; emit rowid = ty*N+src.
__global__ __launch_bounds__(1024) void finescatter_kernel(
    const u32* __restrict__ tmp, const u32* __restrict__ bin_base,
    u32* __restrict__ row_ptr, u32* __restrict__ packed,
    int N, int E, int sh_bin, int sh) {
  __shared__ u32 dcnt[1024];
  __shared__ u32 s[1024];
  const int t = threadIdx.x;
  const int b = blockIdx.x;
  const u32 beg = bin_base[b], end = bin_base[b + 1];
  const int W  = 1 << sh_bin;
  const int d0 = b << sh_bin;
  const int dsh = sh + 3;
  const u32 smask = (1u << sh) - 1u;

  if (t < W) dcnt[t] = 0u;
  __syncthreads();
  for (u32 e = beg + t; e < end; e += 1024)
    atomicAdd(&dcnt[tmp[e] >> dsh], 1u);
  __syncthreads();
  u32 v = (t < W) ? dcnt[t] : 0u;
  s[t] = v;
  __syncthreads();
  for (int off = 1; off < 1024; off <<= 1) {
    u32 x = (t >= off) ? s[t - off] : 0u;
    __syncthreads();
    s[t] += x;
    __syncthreads();
  }
  const u32 ex = s[t] - v;
  if (t < W) {
    int d = d0 + t;
    if (d < N) row_ptr[d] = beg + ex;
    dcnt[t] = beg + ex;                      // cursor
  }
  if (b == 0 && t == 0) row_ptr[N] = (u32)E;
  __syncthreads();
  for (u32 e = beg + t; e < end; e += 1024) {
    u32 p = tmp[e];
    u32 pos = atomicAdd(&dcnt[p >> dsh], 1u);
    u32 src = p & smask;
    u32 ty  = (p >> sh) & 7u;
    packed[pos] = ty * (u32)N + src;         // direct h16 row index
  }
}

// ---------------- per-layer compute ----------------

// Wt16[m][o][k] = bf16( sum_b coeff[m,b]*basis[b,k,o] ) for m<R; self_w[k,o] for m==R.
__global__ __launch_bounds__(256) void compute_wt_kernel(
    const float* __restrict__ basis, const float* __restrict__ coeff,
    const float* __restrict__ self_w, unsigned short* __restrict__ Wt16,
    int R, int Bn) {
  int idx = blockIdx.x * 256 + threadIdx.x;
  int total = (R + 1) * DD * DD;
  if (idx >= total) return;
  int m = idx >> 12;
  int k = (idx >> 6) & 63;
  int o = idx & 63;
  float acc = 0.f;
  if (m == R) {
    acc = self_w[k * DD + o];
  } else {
    for (int b = 0; b < Bn; ++b)
      acc += coeff[m * Bn + b] * basis[((size_t)b * DD + k) * DD + o];
  }
  Wt16[((size_t)m * DD + o) * DD + k] = f2bf(acc);
}

// h16[m][n][o] = bf16( (x @ W_m)[n][o] )  (m==R: x @ self_w, no bias)
// MFMA with swapped operands: D[i=o_local][j=node] -> lane owns 4 consecutive o
// for one node -> single ushort4 (8B) store per tile. Zero LDS.
__global__ __launch_bounds__(256) void transform_h_kernel(
    const float* __restrict__ x, const unsigned short* __restrict__ Wt16,
    unsigned short* __restrict__ h16, int N, int R) {
  const int t    = threadIdx.x;
  const int w    = t >> 6;
  const int lane = t & 63;
  const int l16  = lane & 15;
  const int kg   = lane >> 4;
  const int node = blockIdx.x * DD + w * 16 + l16;   // B col = D col
  const bool ok  = (node < N);

  // X fragment (B operand): B[k][node]; lane reads x[node][kg*8 + kc*32 .. +8)
  bf16x8 Xfrag[2];
  {
    const float* xp = x + (size_t)(ok ? node : 0) * DD + kg * 8;
#pragma unroll
    for (int kc = 0; kc < 2; ++kc) {
      float4 v0 = ok ? *reinterpret_cast<const float4*>(xp + kc * 32)
                     : make_float4(0.f, 0.f, 0.f, 0.f);
      float4 v1 = ok ? *reinterpret_cast<const float4*>(xp + kc * 32 + 4)
                     : make_float4(0.f, 0.f, 0.f, 0.f);
      bf16x8 a;
      a[0] = (short)f2bf(v0.x); a[1] = (short)f2bf(v0.y);
      a[2] = (short)f2bf(v0.z); a[3] = (short)f2bf(v0.w);
      a[4] = (short)f2bf(v1.x); a[5] = (short)f2bf(v1.y);
      a[6] = (short)f2bf(v1.z); a[7] = (short)f2bf(v1.w);
      Xfrag[kc] = a;
    }
  }

  for (int m = 0; m <= R; ++m) {
    const unsigned short* wb = Wt16 + (size_t)m * DD * DD;
    unsigned short* hp = h16 + (((size_t)m * N + node) << 6);
#pragma unroll
    for (int t4 = 0; t4 < 4; ++t4) {
      // A operand: A[i][k] = Wt16[m][t4*16 + i][k]; lane row i=l16, k=kg*8+e
      const unsigned short* ap = wb + ((size_t)(t4 * 16 + l16)) * DD + kg * 8;
      bf16x8 A0 = *reinterpret_cast<const bf16x8*>(ap);
      bf16x8 A1 = *reinterpret_cast<const bf16x8*>(ap + 32);
      f32x4 acc;
      acc[0] = 0.f; acc[1] = 0.f; acc[2] = 0.f; acc[3] = 0.f;
      acc = __builtin_amdgcn_mfma_f32_16x16x32_bf16(A0, Xfrag[0], acc, 0, 0, 0);
      acc = __builtin_amdgcn_mfma_f32_16x16x32_bf16(A1, Xfrag[1], acc, 0, 0, 0);
      if (ok) {
        ushort4 o4;
        o4.x = f2bf(acc[0]); o4.y = f2bf(acc[1]);
        o4.z = f2bf(acc[2]); o4.w = f2bf(acc[3]);
        *reinterpret_cast<ushort4*>(hp + t4 * 16 + kg * 4) = o4;  // o = t4*16+kg*4+r
      }
    }
  }
}

// One wave per destination node. 4 groups x 16 lanes; group g handles edge e+g,
// lane covers features l16*4..+3 (ushort4 = 8B -> 4 edges per dwordx2 issue).
__global__ __launch_bounds__(256) void aggregate_out_kernel(
    const u32* __restrict__ packed, const u32* __restrict__ row_ptr,
    const unsigned short* __restrict__ h16, const float* __restrict__ bias_l,
    float* __restrict__ out, int N, int R) {
  const int wid  = (blockIdx.x * 256 + threadIdx.x) >> 6;
  const int lane = threadIdx.x & 63;
  if (wid >= N) return;
  const int g   = lane >> 4;
  const int l16 = lane & 15;
  const u32 beg = row_ptr[wid], end = row_ptr[wid + 1];
  const u32 cnt = end - beg;

  float s0 = 0.f, s1 = 0.f, s2 = 0.f, s3 = 0.f;
  if (g == 0) {                      // self row (+ bias later), counted once
    const ushort4 v = *reinterpret_cast<const ushort4*>(
        h16 + (((size_t)R * N + wid) << 6) + l16 * 4);
    s0 = bf2f(v.x); s1 = bf2f(v.y); s2 = bf2f(v.z); s3 = bf2f(v.w);
  }

  const u32 main = cnt & ~7u;
  u32 e = beg;
  for (; e < beg + main; e += 8) {
    u32 r0 = packed[e + g];
    u32 r1 = packed[e + 4 + g];
    ushort4 v0 = *reinterpret_cast<const ushort4*>(h16 + ((size_t)r0 << 6) + l16 * 4);
    ushort4 v1 = *reinterpret_cast<const ushort4*>(h16 + ((size_t)r1 << 6) + l16 * 4);
    s0 += bf2f(v0.x) + bf2f(v1.x);
    s1 += bf2f(v0.y) + bf2f(v1.y);
    s2 += bf2f(v0.z) + bf2f(v1.z);
    s3 += bf2f(v0.w) + bf2f(v1.w);
  }
  for (; e < end; e += 4) {
    u32 eg = e + g;
    if (eg < end) {
      u32 r0 = packed[eg];
      ushort4 v0 = *reinterpret_cast<const ushort4*>(h16 + ((size_t)r0 << 6) + l16 * 4);
      s0 += bf2f(v0.x); s1 += bf2f(v0.y); s2 += bf2f(v0.z); s3 += bf2f(v0.w);
    }
  }

  s0 += __shfl_xor(s0, 16); s0 += __shfl_xor(s0, 32);
  s1 += __shfl_xor(s1, 16); s1 += __shfl_xor(s1, 32);
  s2 += __shfl_xor(s2, 16); s2 += __shfl_xor(s2, 32);
  s3 += __shfl_xor(s3, 16); s3 += __shfl_xor(s3, 32);

  if (g == 0) {
    const float4 bv = *reinterpret_cast<const float4*>(bias_l + l16 * 4);
    float4 o;
    o.x = fmaxf(s0 + bv.x, 0.f);
    o.y = fmaxf(s1 + bv.y, 0.f);
    o.z = fmaxf(s2 + bv.z, 0.f);
    o.w = fmaxf(s3 + bv.w, 0.f);
    *reinterpret_cast<float4*>(out + ((size_t)wid << 6) + l16 * 4) = o;
  }
}

extern "C" void kernel_launch(void* const* d_in, const int* in_sizes, int n_in,
                              void* d_out, int out_size, void* d_ws, size_t ws_size,
                              hipStream_t stream) {
  const float* x0     = (const float*)d_in[0];
  const float* basis  = (const float*)d_in[1];
  const float* coeff  = (const float*)d_in[2];
  const float* self_w = (const float*)d_in[3];
  const float* bias   = (const float*)d_in[4];
  const int*   eidx   = (const int*)d_in[5];
  const int*   etyp   = (const int*)d_in[6];

  const int N  = in_sizes[0] / DD;
  const int L  = in_sizes[4] / DD;
  const int Bn = in_sizes[1] / (L * DD * DD);
  const int R  = in_sizes[2] / (L * Bn);
  const int E  = in_sizes[6];

  int sh = 0;
  while ((1 << sh) < N) ++sh;               // src bits (17 at N=100k)
  int sh_bin = 0;
  while ((((N - 1) >> sh_bin) + 1) > 256) ++sh_bin;    // nbins<=256 (sh_bin=9)
  const int nbins = ((N - 1) >> sh_bin) + 1;           // 196 at N=100k

  const int* esrc = eidx;
  const int* edst = eidx + E;

  // ---- workspace layout ----
  u32* row_ptr = (u32*)d_ws;                               // N+1
  u32* packed  = row_ptr + N + 1;                          // E
  size_t u32B  = (((size_t)N + 1 + E) * 4 + 15) / 16 * 16;
  unsigned short* Wt16 = (unsigned short*)((char*)d_ws + u32B);   // (R+1)*DD*DD
  size_t wtB   = (u32B + (size_t)(R + 1) * DD * DD * 2 + 15) / 16 * 16;
  float* A     = (float*)((char*)d_ws + wtB);              // N*DD fp32 intermediate
  unsigned short* h16 = (unsigned short*)(A + (size_t)N * DD);    // (R+1)*N*DD bf16
  // build-phase overlays on h16 region
  u32* ccnt       = (u32*)h16;                             // nbins
  u32* bin_base   = ccnt + 256;                            // nbins+1
  u32* bin_cursor = bin_base + 257;                        // nbins
  u32* tmp        = bin_cursor + 256 + 3;                  // E

  const int nb_bs  = (E + EPB - 1) / EPB;
  const int nb_agg = (int)(((size_t)N * 64 + 255) / 256);
  const int nb_x   = (N + DD - 1) / DD;
  const int nb_wt  = ((R + 1) * DD * DD + 255) / 256;

  // ---- build CSR (once; edges constant across layers) ----
  zero_u32_kernel<<<1, 256, 0, stream>>>(ccnt, nbins);
  coarse_hist_kernel<<<1024, 256, 0, stream>>>(edst, ccnt, E, sh_bin, nbins);
  coarse_scan_kernel<<<1, 256, 0, stream>>>(ccnt, bin_base, bin_cursor, nbins, E);
  binscatter_kernel<<<nb_bs, 256, 0, stream>>>(
      esrc, edst, etyp, bin_cursor, tmp, E, sh_bin, sh, nbins);
  finescatter_kernel<<<nbins, 1024, 0, stream>>>(
      tmp, bin_base, row_ptr, packed, N, E, sh_bin, sh);

  // ---- layers ----
  for (int l = 0; l < L; ++l) {
    const float* xin = (l == 0) ? x0 : A;
    float* outf      = (l == L - 1) ? (float*)d_out : A;

    compute_wt_kernel<<<nb_wt, 256, 0, stream>>>(
        basis + (size_t)l * Bn * DD * DD, coeff + (size_t)l * R * Bn,
        self_w + (size_t)l * DD * DD, Wt16, R, Bn);

    transform_h_kernel<<<nb_x, 256, 0, stream>>>(xin, Wt16, h16, N, R);

    aggregate_out_kernel<<<nb_agg, 256, 0, stream>>>(
        packed, row_ptr, h16, bias + (size_t)l * DD, outf, N, R);
  }
}

// Round 11
// 332.167 us; speedup vs baseline: 2.9756x; 1.1989x over previous
//
#include <hip/hip_runtime.h>
#include <hip/hip_bf16.h>

#define DD 64
#define EPB 8192   // edges per binscatter block (32 per thread)
#define WPAD 72    // padded LDS row stride (ushorts): 144B, 16B-aligned, ~2-way banks

typedef unsigned int u32;
typedef __attribute__((ext_vector_type(8))) short bf16x8;
typedef __attribute__((ext_vector_type(8))) unsigned short u16x8;
typedef __attribute__((ext_vector_type(4))) float f32x4;

__device__ __forceinline__ float bf2f(unsigned short u) {
  union { u32 i; float f; } c;
  c.i = ((u32)u) << 16;
  return c.f;
}
__device__ __forceinline__ unsigned short f2bf(float f) {
  __hip_bfloat16 h = __float2bfloat16(f);
  return *reinterpret_cast<unsigned short*>(&h);
}

// ---------------- preprocessing: two-level binned CSR build ----------------
// coarse bins: bn = dst >> sh_bin, nbins <= 256.
// tmp record: src | ty << sh | dlow << (sh+3)   (17+3+10 <= 32 bits)
// final packed record: rowid = ty*N + src  (direct h16 row index)

__global__ __launch_bounds__(256) void zero_u32_kernel(u32* __restrict__ p, int n) {
  int i = blockIdx.x * 256 + threadIdx.x;
  if (i < n) p[i] = 0u;
}

__global__ __launch_bounds__(256) void coarse_hist_kernel(
    const int* __restrict__ edst, u32* __restrict__ ccnt,
    int E, int sh_bin, int nbins) {
  __shared__ u32 lh[256];
  const int t = threadIdx.x;
  for (int j = t; j < nbins; j += 256) lh[j] = 0u;
  __syncthreads();
  for (int e = blockIdx.x * 256 + t; e < E; e += gridDim.x * 256)
    atomicAdd(&lh[edst[e] >> sh_bin], 1u);
  __syncthreads();
  for (int j = t; j < nbins; j += 256) {
    u32 c = lh[j];
    if (c) atomicAdd(&ccnt[j], c);
  }
}

__global__ __launch_bounds__(256) void coarse_scan_kernel(
    const u32* __restrict__ ccnt, u32* __restrict__ bin_base,
    u32* __restrict__ bin_cursor, int nbins, int E) {
  __shared__ u32 s[256];
  const int t = threadIdx.x;
  u32 v = (t < nbins) ? ccnt[t] : 0u;
  s[t] = v;
  __syncthreads();
  for (int off = 1; off < 256; off <<= 1) {
    u32 x = (t >= off) ? s[t - off] : 0u;
    __syncthreads();
    s[t] += x;
    __syncthreads();
  }
  if (t < nbins) {
    u32 ex = s[t] - v;
    bin_base[t] = ex;
    bin_cursor[t] = ex;
  }
  if (t == 0) bin_base[nbins] = (u32)E;
}

__global__ __launch_bounds__(256) void binscatter_kernel(
    const int* __restrict__ esrc, const int* __restrict__ edst,
    const int* __restrict__ et, u32* __restrict__ bin_cursor,
    u32* __restrict__ tmp, int E, int sh_bin, int sh, int nbins) {
  __shared__ u32 lhist[256];
  __shared__ u32 lbase[256];
  const int t = threadIdx.x;
  const int base = blockIdx.x * EPB;
  for (int j = t; j < nbins; j += 256) lhist[j] = 0u;
  __syncthreads();
  u32 br[32];
#pragma unroll
  for (int k = 0; k < 32; ++k) {
    int e = base + k * 256 + t;
    if (e < E) {
      int bn = edst[e] >> sh_bin;
      u32 r = atomicAdd(&lhist[bn], 1u);
      br[k] = ((u32)bn << 13) | r;           // bn<256, r<8192
    }
  }
  __syncthreads();
  for (int j = t; j < nbins; j += 256) {
    u32 c = lhist[j];
    lbase[j] = c ? atomicAdd(&bin_cursor[j], c) : 0u;
  }
  __syncthreads();
  const u32 wmask = (1u << sh_bin) - 1u;
#pragma unroll
  for (int k = 0; k < 32; ++k) {
    int e = base + k * 256 + t;
    if (e < E) {
      u32 bn = br[k] >> 13, r = br[k] & 0x1FFFu;
      u32 pos = lbase[bn] + r;
      u32 dlow = (u32)edst[e] & wmask;
      tmp[pos] = (u32)esrc[e] | ((u32)et[e] << sh) | (dlow << (sh + 3));
    }
  }
}

// One block per bin: LDS fine hist + scan -> row_ptr slice; emit rowid = ty*N+src.
__global__ __launch_bounds__(1024) void finescatter_kernel(
    const u32* __restrict__ tmp, const u32* __restrict__ bin_base,
    u32* __restrict__ row_ptr, u32* __restrict__ packed,
    int N, int E, int sh_bin, int sh) {
  __shared__ u32 dcnt[1024];
  __shared__ u32 s[1024];
  const int t = threadIdx.x;
  const int b = blockIdx.x;
  const u32 beg = bin_base[b], end = bin_base[b + 1];
  const int W  = 1 << sh_bin;
  const int d0 = b << sh_bin;
  const int dsh = sh + 3;
  const u32 smask = (1u << sh) - 1u;

  if (t < W) dcnt[t] = 0u;
  __syncthreads();
  for (u32 e = beg + t; e < end; e += 1024)
    atomicAdd(&dcnt[tmp[e] >> dsh], 1u);
  __syncthreads();
  u32 v = (t < W) ? dcnt[t] : 0u;
  s[t] = v;
  __syncthreads();
  for (int off = 1; off < 1024; off <<= 1) {
    u32 x = (t >= off) ? s[t - off] : 0u;
    __syncthreads();
    s[t] += x;
    __syncthreads();
  }
  const u32 ex = s[t] - v;
  if (t < W) {
    int d = d0 + t;
    if (d < N) row_ptr[d] = beg + ex;
    dcnt[t] = beg + ex;                      // cursor
  }
  if (b == 0 && t == 0) row_ptr[N] = (u32)E;
  __syncthreads();
  for (u32 e = beg + t; e < end; e += 1024) {
    u32 p = tmp[e];
    u32 pos = atomicAdd(&dcnt[p >> dsh], 1u);
    u32 src = p & smask;
    u32 ty  = (p >> sh) & 7u;
    packed[pos] = ty * (u32)N + src;         // direct h16 row index
  }
}

// ---------------- per-layer compute ----------------

// Wt16[m][o][k] = bf16( sum_b coeff[m,b]*basis[b,k,o] ) for m<R; self_w[k,o] for m==R.
__global__ __launch_bounds__(256) void compute_wt_kernel(
    const float* __restrict__ basis, const float* __restrict__ coeff,
    const float* __restrict__ self_w, unsigned short* __restrict__ Wt16,
    int R, int Bn) {
  int idx = blockIdx.x * 256 + threadIdx.x;
  int total = (R + 1) * DD * DD;
  if (idx >= total) return;
  int m = idx >> 12;
  int k = (idx >> 6) & 63;
  int o = idx & 63;
  float acc = 0.f;
  if (m == R) {
    acc = self_w[k * DD + o];
  } else {
    for (int b = 0; b < Bn; ++b)
      acc += coeff[m * Bn + b] * basis[((size_t)b * DD + k) * DD + o];
  }
  Wt16[((size_t)m * DD + o) * DD + k] = f2bf(acc);
}

// h16[m][n][o] = bf16( (x @ W_m)[n][o] )  (m==R: x @ self_w, no bias)
// MFMA swapped operands (D[o][node]); Wt16 staged per-m in double-buffered LDS:
// stage m+1 issued BEFORE computing m so global latency hides under MFMAs.
__global__ __launch_bounds__(256) void transform_h_kernel(
    const float* __restrict__ x, const unsigned short* __restrict__ Wt16,
    unsigned short* __restrict__ h16, int N, int R) {
  __shared__ unsigned short Ws[2][64 * WPAD];
  const int t    = threadIdx.x;
  const int w    = t >> 6;
  const int lane = t & 63;
  const int l16  = lane & 15;
  const int kg   = lane >> 4;
  const int node = blockIdx.x * DD + w * 16 + l16;   // B col = D col
  const bool ok  = (node < N);

  // X fragment (B operand): B[k][node]; lane reads x[node][kg*8 + kc*32 .. +8)
  bf16x8 Xfrag[2];
  {
    const float* xp = x + (size_t)(ok ? node : 0) * DD + kg * 8;
#pragma unroll
    for (int kc = 0; kc < 2; ++kc) {
      float4 v0 = ok ? *reinterpret_cast<const float4*>(xp + kc * 32)
                     : make_float4(0.f, 0.f, 0.f, 0.f);
      float4 v1 = ok ? *reinterpret_cast<const float4*>(xp + kc * 32 + 4)
                     : make_float4(0.f, 0.f, 0.f, 0.f);
      bf16x8 a;
      a[0] = (short)f2bf(v0.x); a[1] = (short)f2bf(v0.y);
      a[2] = (short)f2bf(v0.z); a[3] = (short)f2bf(v0.w);
      a[4] = (short)f2bf(v1.x); a[5] = (short)f2bf(v1.y);
      a[6] = (short)f2bf(v1.z); a[7] = (short)f2bf(v1.w);
      Xfrag[kc] = a;
    }
  }

  // stage m=0 into buffer 0 (32B/thread, coalesced)
  {
#pragma unroll
    for (int i = 0; i < 2; ++i) {
      int q = t + (i << 8);                 // 0..511
      int row = q >> 3, c8 = (q & 7) << 3;  // 64 rows x 8 chunks of 8 ushorts
      u16x8 v = *reinterpret_cast<const u16x8*>(Wt16 + row * DD + c8);
      *reinterpret_cast<u16x8*>(&Ws[0][row * WPAD + c8]) = v;
    }
  }
  __syncthreads();

  for (int m = 0; m <= R; ++m) {
    const int cur = m & 1;
    // issue next matrix staging first: global latency hides under this m's MFMAs
    if (m < R) {
      const unsigned short* wb = Wt16 + ((size_t)(m + 1) << 12);
#pragma unroll
      for (int i = 0; i < 2; ++i) {
        int q = t + (i << 8);
        int row = q >> 3, c8 = (q & 7) << 3;
        u16x8 v = *reinterpret_cast<const u16x8*>(wb + row * DD + c8);
        *reinterpret_cast<u16x8*>(&Ws[cur ^ 1][row * WPAD + c8]) = v;
      }
    }

    unsigned short* hp = h16 + (((size_t)m * N + node) << 6);
#pragma unroll
    for (int t4 = 0; t4 < 4; ++t4) {
      // A operand from LDS: A[i][k] = Ws[cur][t4*16 + i][k]; lane row i=l16
      const unsigned short* ap = &Ws[cur][(t4 * 16 + l16) * WPAD + kg * 8];
      bf16x8 A0 = *reinterpret_cast<const bf16x8*>(ap);
      bf16x8 A1 = *reinterpret_cast<const bf16x8*>(ap + 32);
      f32x4 acc;
      acc[0] = 0.f; acc[1] = 0.f; acc[2] = 0.f; acc[3] = 0.f;
      acc = __builtin_amdgcn_mfma_f32_16x16x32_bf16(A0, Xfrag[0], acc, 0, 0, 0);
      acc = __builtin_amdgcn_mfma_f32_16x16x32_bf16(A1, Xfrag[1], acc, 0, 0, 0);
      if (ok) {
        ushort4 o4;
        o4.x = f2bf(acc[0]); o4.y = f2bf(acc[1]);
        o4.z = f2bf(acc[2]); o4.w = f2bf(acc[3]);
        *reinterpret_cast<ushort4*>(hp + t4 * 16 + kg * 4) = o4;  // o = t4*16+kg*4+r
      }
    }
    __syncthreads();   // staging of m+1 done; reads of buf[cur] done before reuse
  }
}

// One wave per destination node. 4 groups x 16 lanes; group g handles edge e+g,
// lane covers features l16*4..+3 (ushort4 = 8B -> 4 edges per dwordx2 issue).
__global__ __launch_bounds__(256) void aggregate_out_kernel(
    const u32* __restrict__ packed, const u32* __restrict__ row_ptr,
    const unsigned short* __restrict__ h16, const float* __restrict__ bias_l,
    float* __restrict__ out, int N, int R) {
  const int wid  = (blockIdx.x * 256 + threadIdx.x) >> 6;
  const int lane = threadIdx.x & 63;
  if (wid >= N) return;
  const int g   = lane >> 4;
  const int l16 = lane & 15;
  const u32 beg = row_ptr[wid], end = row_ptr[wid + 1];
  const u32 cnt = end - beg;

  float s0 = 0.f, s1 = 0.f, s2 = 0.f, s3 = 0.f;
  if (g == 0) {                      // self row (+ bias later), counted once
    const ushort4 v = *reinterpret_cast<const ushort4*>(
        h16 + (((size_t)R * N + wid) << 6) + l16 * 4);
    s0 = bf2f(v.x); s1 = bf2f(v.y); s2 = bf2f(v.z); s3 = bf2f(v.w);
  }

  const u32 main = cnt & ~7u;
  u32 e = beg;
  for (; e < beg + main; e += 8) {
    u32 r0 = packed[e + g];
    u32 r1 = packed[e + 4 + g];
    ushort4 v0 = *reinterpret_cast<const ushort4*>(h16 + ((size_t)r0 << 6) + l16 * 4);
    ushort4 v1 = *reinterpret_cast<const ushort4*>(h16 + ((size_t)r1 << 6) + l16 * 4);
    s0 += bf2f(v0.x) + bf2f(v1.x);
    s1 += bf2f(v0.y) + bf2f(v1.y);
    s2 += bf2f(v0.z) + bf2f(v1.z);
    s3 += bf2f(v0.w) + bf2f(v1.w);
  }
  for (; e < end; e += 4) {
    u32 eg = e + g;
    if (eg < end) {
      u32 r0 = packed[eg];
      ushort4 v0 = *reinterpret_cast<const ushort4*>(h16 + ((size_t)r0 << 6) + l16 * 4);
      s0 += bf2f(v0.x); s1 += bf2f(v0.y); s2 += bf2f(v0.z); s3 += bf2f(v0.w);
    }
  }

  s0 += __shfl_xor(s0, 16); s0 += __shfl_xor(s0, 32);
  s1 += __shfl_xor(s1, 16); s1 += __shfl_xor(s1, 32);
  s2 += __shfl_xor(s2, 16); s2 += __shfl_xor(s2, 32);
  s3 += __shfl_xor(s3, 16); s3 += __shfl_xor(s3, 32);

  if (g == 0) {
    const float4 bv = *reinterpret_cast<const float4*>(bias_l + l16 * 4);
    float4 o;
    o.x = fmaxf(s0 + bv.x, 0.f);
    o.y = fmaxf(s1 + bv.y, 0.f);
    o.z = fmaxf(s2 + bv.z, 0.f);
    o.w = fmaxf(s3 + bv.w, 0.f);
    *reinterpret_cast<float4*>(out + ((size_t)wid << 6) + l16 * 4) = o;
  }
}

extern "C" void kernel_launch(void* const* d_in, const int* in_sizes, int n_in,
                              void* d_out, int out_size, void* d_ws, size_t ws_size,
                              hipStream_t stream) {
  const float* x0     = (const float*)d_in[0];
  const float* basis  = (const float*)d_in[1];
  const float* coeff  = (const float*)d_in[2];
  const float* self_w = (const float*)d_in[3];
  const float* bias   = (const float*)d_in[4];
  const int*   eidx   = (const int*)d_in[5];
  const int*   etyp   = (const int*)d_in[6];

  const int N  = in_sizes[0] / DD;
  const int L  = in_sizes[4] / DD;
  const int Bn = in_sizes[1] / (L * DD * DD);
  const int R  = in_sizes[2] / (L * Bn);
  const int E  = in_sizes[6];

  int sh = 0;
  while ((1 << sh) < N) ++sh;               // src bits (17 at N=100k)
  int sh_bin = 0;
  while ((((N - 1) >> sh_bin) + 1) > 256) ++sh_bin;    // nbins<=256 (sh_bin=9)
  const int nbins = ((N - 1) >> sh_bin) + 1;           // 196 at N=100k

  const int* esrc = eidx;
  const int* edst = eidx + E;

  // ---- workspace layout ----
  u32* row_ptr = (u32*)d_ws;                               // N+1
  u32* packed  = row_ptr + N + 1;                          // E
  size_t u32B  = (((size_t)N + 1 + E) * 4 + 15) / 16 * 16;
  unsigned short* Wt16 = (unsigned short*)((char*)d_ws + u32B);   // (R+1)*DD*DD
  size_t wtB   = (u32B + (size_t)(R + 1) * DD * DD * 2 + 15) / 16 * 16;
  float* A     = (float*)((char*)d_ws + wtB);              // N*DD fp32 intermediate
  unsigned short* h16 = (unsigned short*)(A + (size_t)N * DD);    // (R+1)*N*DD bf16
  // build-phase overlays on h16 region
  u32* ccnt       = (u32*)h16;                             // nbins
  u32* bin_base   = ccnt + 256;                            // nbins+1
  u32* bin_cursor = bin_base + 257;                        // nbins
  u32* tmp        = bin_cursor + 256 + 3;                  // E

  const int nb_bs  = (E + EPB - 1) / EPB;
  const int nb_agg = (int)(((size_t)N * 64 + 255) / 256);
  const int nb_x   = (N + DD - 1) / DD;
  const int nb_wt  = ((R + 1) * DD * DD + 255) / 256;

  // ---- build CSR (once; edges constant across layers) ----
  zero_u32_kernel<<<1, 256, 0, stream>>>(ccnt, nbins);
  coarse_hist_kernel<<<1024, 256, 0, stream>>>(edst, ccnt, E, sh_bin, nbins);
  coarse_scan_kernel<<<1, 256, 0, stream>>>(ccnt, bin_base, bin_cursor, nbins, E);
  binscatter_kernel<<<nb_bs, 256, 0, stream>>>(
      esrc, edst, etyp, bin_cursor, tmp, E, sh_bin, sh, nbins);
  finescatter_kernel<<<nbins, 1024, 0, stream>>>(
      tmp, bin_base, row_ptr, packed, N, E, sh_bin, sh);

  // ---- layers ----
  for (int l = 0; l < L; ++l) {
    const float* xin = (l == 0) ? x0 : A;
    float* outf      = (l == L - 1) ? (float*)d_out : A;

    compute_wt_kernel<<<nb_wt, 256, 0, stream>>>(
        basis + (size_t)l * Bn * DD * DD, coeff + (size_t)l * R * Bn,
        self_w + (size_t)l * DD * DD, Wt16, R, Bn);

    transform_h_kernel<<<nb_x, 256, 0, stream>>>(xin, Wt16, h16, N, R);

    aggregate_out_kernel<<<nb_agg, 256, 0, stream>>>(
        packed, row_ptr, h16, bias + (size_t)l * DD, outf, N, R);
  }
}

// Round 12
// 330.032 us; speedup vs baseline: 2.9949x; 1.0065x over previous
//
#include <hip/hip_runtime.h>
#include <hip/hip_bf16.h>

#define DD 64
#define EPB 8192   // edges per binscatter block (32 per thread)
#define WPAD 72    // padded LDS row stride (ushorts): 144B, 16B-aligned, ~2-way banks

typedef unsigned int u32;
typedef __attribute__((ext_vector_type(8))) short bf16x8;
typedef __attribute__((ext_vector_type(8))) unsigned short u16x8;
typedef __attribute__((ext_vector_type(4))) float f32x4;

__device__ __forceinline__ float bf2f(unsigned short u) {
  union { u32 i; float f; } c;
  c.i = ((u32)u) << 16;
  return c.f;
}
__device__ __forceinline__ unsigned short f2bf(float f) {
  __hip_bfloat16 h = __float2bfloat16(f);
  return *reinterpret_cast<unsigned short*>(&h);
}

// ---------------- preprocessing: two-level binned CSR build ----------------
// coarse bins: bn = dst >> sh_bin, nbins <= 256.
// tmp record: src | ty << sh | dlow << (sh+3)   (17+3+10 <= 32 bits)
// final packed record: rowid = ty*N + src  (direct h16 row index)

__global__ __launch_bounds__(256) void zero_u32_kernel(u32* __restrict__ p, int n) {
  int i = blockIdx.x * 256 + threadIdx.x;
  if (i < n) p[i] = 0u;
}

__global__ __launch_bounds__(256) void coarse_hist_kernel(
    const int* __restrict__ edst, u32* __restrict__ ccnt,
    int E, int sh_bin, int nbins) {
  __shared__ u32 lh[256];
  const int t = threadIdx.x;
  for (int j = t; j < nbins; j += 256) lh[j] = 0u;
  __syncthreads();
  for (int e = blockIdx.x * 256 + t; e < E; e += gridDim.x * 256)
    atomicAdd(&lh[edst[e] >> sh_bin], 1u);
  __syncthreads();
  for (int j = t; j < nbins; j += 256) {
    u32 c = lh[j];
    if (c) atomicAdd(&ccnt[j], c);
  }
}

__global__ __launch_bounds__(256) void coarse_scan_kernel(
    const u32* __restrict__ ccnt, u32* __restrict__ bin_base,
    u32* __restrict__ bin_cursor, int nbins, int E) {
  __shared__ u32 s[256];
  const int t = threadIdx.x;
  u32 v = (t < nbins) ? ccnt[t] : 0u;
  s[t] = v;
  __syncthreads();
  for (int off = 1; off < 256; off <<= 1) {
    u32 x = (t >= off) ? s[t - off] : 0u;
    __syncthreads();
    s[t] += x;
    __syncthreads();
  }
  if (t < nbins) {
    u32 ex = s[t] - v;
    bin_base[t] = ex;
    bin_cursor[t] = ex;
  }
  if (t == 0) bin_base[nbins] = (u32)E;
}

__global__ __launch_bounds__(256) void binscatter_kernel(
    const int* __restrict__ esrc, const int* __restrict__ edst,
    const int* __restrict__ et, u32* __restrict__ bin_cursor,
    u32* __restrict__ tmp, int E, int sh_bin, int sh, int nbins) {
  __shared__ u32 lhist[256];
  __shared__ u32 lbase[256];
  const int t = threadIdx.x;
  const int base = blockIdx.x * EPB;
  for (int j = t; j < nbins; j += 256) lhist[j] = 0u;
  __syncthreads();
  u32 br[32];
#pragma unroll
  for (int k = 0; k < 32; ++k) {
    int e = base + k * 256 + t;
    if (e < E) {
      int bn = edst[e] >> sh_bin;
      u32 r = atomicAdd(&lhist[bn], 1u);
      br[k] = ((u32)bn << 13) | r;           // bn<256, r<8192
    }
  }
  __syncthreads();
  for (int j = t; j < nbins; j += 256) {
    u32 c = lhist[j];
    lbase[j] = c ? atomicAdd(&bin_cursor[j], c) : 0u;
  }
  __syncthreads();
  const u32 wmask = (1u << sh_bin) - 1u;
#pragma unroll
  for (int k = 0; k < 32; ++k) {
    int e = base + k * 256 + t;
    if (e < E) {
      u32 bn = br[k] >> 13, r = br[k] & 0x1FFFu;
      u32 pos = lbase[bn] + r;
      u32 dlow = (u32)edst[e] & wmask;
      tmp[pos] = (u32)esrc[e] | ((u32)et[e] << sh) | (dlow << (sh + 3));
    }
  }
}

// One block per bin: LDS fine hist + scan -> row_ptr slice; emit rowid = ty*N+src.
__global__ __launch_bounds__(1024) void finescatter_kernel(
    const u32* __restrict__ tmp, const u32* __restrict__ bin_base,
    u32* __restrict__ row_ptr, u32* __restrict__ packed,
    int N, int E, int sh_bin, int sh) {
  __shared__ u32 dcnt[1024];
  __shared__ u32 s[1024];
  const int t = threadIdx.x;
  const int b = blockIdx.x;
  const u32 beg = bin_base[b], end = bin_base[b + 1];
  const int W  = 1 << sh_bin;
  const int d0 = b << sh_bin;
  const int dsh = sh + 3;
  const u32 smask = (1u << sh) - 1u;

  if (t < W) dcnt[t] = 0u;
  __syncthreads();
  for (u32 e = beg + t; e < end; e += 1024)
    atomicAdd(&dcnt[tmp[e] >> dsh], 1u);
  __syncthreads();
  u32 v = (t < W) ? dcnt[t] : 0u;
  s[t] = v;
  __syncthreads();
  for (int off = 1; off < 1024; off <<= 1) {
    u32 x = (t >= off) ? s[t - off] : 0u;
    __syncthreads();
    s[t] += x;
    __syncthreads();
  }
  const u32 ex = s[t] - v;
  if (t < W) {
    int d = d0 + t;
    if (d < N) row_ptr[d] = beg + ex;
    dcnt[t] = beg + ex;                      // cursor
  }
  if (b == 0 && t == 0) row_ptr[N] = (u32)E;
  __syncthreads();
  for (u32 e = beg + t; e < end; e += 1024) {
    u32 p = tmp[e];
    u32 pos = atomicAdd(&dcnt[p >> dsh], 1u);
    u32 src = p & smask;
    u32 ty  = (p >> sh) & 7u;
    packed[pos] = ty * (u32)N + src;         // direct h16 row index
  }
}

// ---------------- per-layer compute ----------------

// Wt16[m][o][k] = bf16( sum_b coeff[m,b]*basis[b,k,o] ) for m<R; self_w[k,o] for m==R.
__global__ __launch_bounds__(256) void compute_wt_kernel(
    const float* __restrict__ basis, const float* __restrict__ coeff,
    const float* __restrict__ self_w, unsigned short* __restrict__ Wt16,
    int R, int Bn) {
  int idx = blockIdx.x * 256 + threadIdx.x;
  int total = (R + 1) * DD * DD;
  if (idx >= total) return;
  int m = idx >> 12;
  int k = (idx >> 6) & 63;
  int o = idx & 63;
  float acc = 0.f;
  if (m == R) {
    acc = self_w[k * DD + o];
  } else {
    for (int b = 0; b < Bn; ++b)
      acc += coeff[m * Bn + b] * basis[((size_t)b * DD + k) * DD + o];
  }
  Wt16[((size_t)m * DD + o) * DD + k] = f2bf(acc);
}

// h16[m][n][o] = bf16( (x @ W_m)[n][o] )  (m==R: x @ self_w, no bias)
// MFMA swapped operands (D[o][node]); Wt16 staged per-m in double-buffered LDS:
// stage m+1 issued BEFORE computing m so global latency hides under MFMAs.
__global__ __launch_bounds__(256) void transform_h_kernel(
    const float* __restrict__ x, const unsigned short* __restrict__ Wt16,
    unsigned short* __restrict__ h16, int N, int R) {
  __shared__ unsigned short Ws[2][64 * WPAD];
  const int t    = threadIdx.x;
  const int w    = t >> 6;
  const int lane = t & 63;
  const int l16  = lane & 15;
  const int kg   = lane >> 4;
  const int node = blockIdx.x * DD + w * 16 + l16;   // B col = D col
  const bool ok  = (node < N);

  // X fragment (B operand): B[k][node]; lane reads x[node][kg*8 + kc*32 .. +8)
  bf16x8 Xfrag[2];
  {
    const float* xp = x + (size_t)(ok ? node : 0) * DD + kg * 8;
#pragma unroll
    for (int kc = 0; kc < 2; ++kc) {
      float4 v0 = ok ? *reinterpret_cast<const float4*>(xp + kc * 32)
                     : make_float4(0.f, 0.f, 0.f, 0.f);
      float4 v1 = ok ? *reinterpret_cast<const float4*>(xp + kc * 32 + 4)
                     : make_float4(0.f, 0.f, 0.f, 0.f);
      bf16x8 a;
      a[0] = (short)f2bf(v0.x); a[1] = (short)f2bf(v0.y);
      a[2] = (short)f2bf(v0.z); a[3] = (short)f2bf(v0.w);
      a[4] = (short)f2bf(v1.x); a[5] = (short)f2bf(v1.y);
      a[6] = (short)f2bf(v1.z); a[7] = (short)f2bf(v1.w);
      Xfrag[kc] = a;
    }
  }

  // stage m=0 into buffer 0 (32B/thread, coalesced)
  {
#pragma unroll
    for (int i = 0; i < 2; ++i) {
      int q = t + (i << 8);                 // 0..511
      int row = q >> 3, c8 = (q & 7) << 3;  // 64 rows x 8 chunks of 8 ushorts
      u16x8 v = *reinterpret_cast<const u16x8*>(Wt16 + row * DD + c8);
      *reinterpret_cast<u16x8*>(&Ws[0][row * WPAD + c8]) = v;
    }
  }
  __syncthreads();

  for (int m = 0; m <= R; ++m) {
    const int cur = m & 1;
    // issue next matrix staging first: global latency hides under this m's MFMAs
    if (m < R) {
      const unsigned short* wb = Wt16 + ((size_t)(m + 1) << 12);
#pragma unroll
      for (int i = 0; i < 2; ++i) {
        int q = t + (i << 8);
        int row = q >> 3, c8 = (q & 7) << 3;
        u16x8 v = *reinterpret_cast<const u16x8*>(wb + row * DD + c8);
        *reinterpret_cast<u16x8*>(&Ws[cur ^ 1][row * WPAD + c8]) = v;
      }
    }

    unsigned short* hp = h16 + (((size_t)m * N + node) << 6);
#pragma unroll
    for (int t4 = 0; t4 < 4; ++t4) {
      // A operand from LDS: A[i][k] = Ws[cur][t4*16 + i][k]; lane row i=l16
      const unsigned short* ap = &Ws[cur][(t4 * 16 + l16) * WPAD + kg * 8];
      bf16x8 A0 = *reinterpret_cast<const bf16x8*>(ap);
      bf16x8 A1 = *reinterpret_cast<const bf16x8*>(ap + 32);
      f32x4 acc;
      acc[0] = 0.f; acc[1] = 0.f; acc[2] = 0.f; acc[3] = 0.f;
      acc = __builtin_amdgcn_mfma_f32_16x16x32_bf16(A0, Xfrag[0], acc, 0, 0, 0);
      acc = __builtin_amdgcn_mfma_f32_16x16x32_bf16(A1, Xfrag[1], acc, 0, 0, 0);
      if (ok) {
        ushort4 o4;
        o4.x = f2bf(acc[0]); o4.y = f2bf(acc[1]);
        o4.z = f2bf(acc[2]); o4.w = f2bf(acc[3]);
        *reinterpret_cast<ushort4*>(hp + t4 * 16 + kg * 4) = o4;  // o = t4*16+kg*4+r
      }
    }
    __syncthreads();   // staging of m+1 done; reads of buf[cur] done before reuse
  }
}

// One wave per destination node. 8 groups x 8 lanes; group g handles edge e+g,
// lane loads ushort8 (16B dwordx4) = features l8*8..+7  -> 8 edges (1KB) per issue.
__global__ __launch_bounds__(256) void aggregate_out_kernel(
    const u32* __restrict__ packed, const u32* __restrict__ row_ptr,
    const unsigned short* __restrict__ h16, const float* __restrict__ bias_l,
    float* __restrict__ out, int N, int R) {
  const int wid  = (blockIdx.x * 256 + threadIdx.x) >> 6;
  const int lane = threadIdx.x & 63;
  if (wid >= N) return;
  const int g  = lane >> 3;      // 0..7: edge slot
  const int l8 = lane & 7;       // 16B chunk within row
  const u32 beg = row_ptr[wid], end = row_ptr[wid + 1];

  float s[8];
  if (g == 0) {                  // self row, counted once
    u16x8 v = *reinterpret_cast<const u16x8*>(
        h16 + (((size_t)R * N + wid) << 6) + l8 * 8);
#pragma unroll
    for (int j = 0; j < 8; ++j) s[j] = bf2f((unsigned short)v[j]);
  } else {
#pragma unroll
    for (int j = 0; j < 8; ++j) s[j] = 0.f;
  }

  const u32 cnt = end - beg;
  u32 e = beg;
  const u32 end16 = beg + (cnt & ~15u);
  for (; e < end16; e += 16) {   // two 1KB gathers in flight
    u32 r0 = packed[e + g];
    u32 r1 = packed[e + 8 + g];
    u16x8 v0 = *reinterpret_cast<const u16x8*>(h16 + ((size_t)r0 << 6) + l8 * 8);
    u16x8 v1 = *reinterpret_cast<const u16x8*>(h16 + ((size_t)r1 << 6) + l8 * 8);
#pragma unroll
    for (int j = 0; j < 8; ++j)
      s[j] += bf2f((unsigned short)v0[j]) + bf2f((unsigned short)v1[j]);
  }
  if (e + 8 <= end) {
    u32 r0 = packed[e + g];
    u16x8 v0 = *reinterpret_cast<const u16x8*>(h16 + ((size_t)r0 << 6) + l8 * 8);
#pragma unroll
    for (int j = 0; j < 8; ++j) s[j] += bf2f((unsigned short)v0[j]);
    e += 8;
  }
  if (e < end) {                 // masked tail (<8 edges)
    u32 eg = e + g;
    if (eg < end) {
      u32 r0 = packed[eg];
      u16x8 v0 = *reinterpret_cast<const u16x8*>(h16 + ((size_t)r0 << 6) + l8 * 8);
#pragma unroll
      for (int j = 0; j < 8; ++j) s[j] += bf2f((unsigned short)v0[j]);
    }
  }

  // reduce across the 8 edge-groups (lanes with same l8)
#pragma unroll
  for (int j = 0; j < 8; ++j) {
    s[j] += __shfl_xor(s[j], 8);
    s[j] += __shfl_xor(s[j], 16);
    s[j] += __shfl_xor(s[j], 32);
  }

  if (g == 0) {
    const float* bp = bias_l + l8 * 8;
    float4 o0, o1;
    o0.x = fmaxf(s[0] + bp[0], 0.f);
    o0.y = fmaxf(s[1] + bp[1], 0.f);
    o0.z = fmaxf(s[2] + bp[2], 0.f);
    o0.w = fmaxf(s[3] + bp[3], 0.f);
    o1.x = fmaxf(s[4] + bp[4], 0.f);
    o1.y = fmaxf(s[5] + bp[5], 0.f);
    o1.z = fmaxf(s[6] + bp[6], 0.f);
    o1.w = fmaxf(s[7] + bp[7], 0.f);
    float* op = out + ((size_t)wid << 6) + l8 * 8;
    *reinterpret_cast<float4*>(op) = o0;
    *reinterpret_cast<float4*>(op + 4) = o1;
  }
}

extern "C" void kernel_launch(void* const* d_in, const int* in_sizes, int n_in,
                              void* d_out, int out_size, void* d_ws, size_t ws_size,
                              hipStream_t stream) {
  const float* x0     = (const float*)d_in[0];
  const float* basis  = (const float*)d_in[1];
  const float* coeff  = (const float*)d_in[2];
  const float* self_w = (const float*)d_in[3];
  const float* bias   = (const float*)d_in[4];
  const int*   eidx   = (const int*)d_in[5];
  const int*   etyp   = (const int*)d_in[6];

  const int N  = in_sizes[0] / DD;
  const int L  = in_sizes[4] / DD;
  const int Bn = in_sizes[1] / (L * DD * DD);
  const int R  = in_sizes[2] / (L * Bn);
  const int E  = in_sizes[6];

  int sh = 0;
  while ((1 << sh) < N) ++sh;               // src bits (17 at N=100k)
  int sh_bin = 0;
  while ((((N - 1) >> sh_bin) + 1) > 256) ++sh_bin;    // nbins<=256 (sh_bin=9)
  const int nbins = ((N - 1) >> sh_bin) + 1;           // 196 at N=100k

  const int* esrc = eidx;
  const int* edst = eidx + E;

  // ---- workspace layout ----
  u32* row_ptr = (u32*)d_ws;                               // N+1
  u32* packed  = row_ptr + N + 1;                          // E
  size_t u32B  = (((size_t)N + 1 + E) * 4 + 15) / 16 * 16;
  unsigned short* Wt16 = (unsigned short*)((char*)d_ws + u32B);   // (R+1)*DD*DD
  size_t wtB   = (u32B + (size_t)(R + 1) * DD * DD * 2 + 15) / 16 * 16;
  float* A     = (float*)((char*)d_ws + wtB);              // N*DD fp32 intermediate
  unsigned short* h16 = (unsigned short*)(A + (size_t)N * DD);    // (R+1)*N*DD bf16
  // build-phase overlays on h16 region
  u32* ccnt       = (u32*)h16;                             // nbins
  u32* bin_base   = ccnt + 256;                            // nbins+1
  u32* bin_cursor = bin_base + 257;                        // nbins
  u32* tmp        = bin_cursor + 256 + 3;                  // E

  const int nb_bs  = (E + EPB - 1) / EPB;
  const int nb_agg = (int)(((size_t)N * 64 + 255) / 256);
  const int nb_x   = (N + DD - 1) / DD;
  const int nb_wt  = ((R + 1) * DD * DD + 255) / 256;

  // ---- build CSR (once; edges constant across layers) ----
  zero_u32_kernel<<<1, 256, 0, stream>>>(ccnt, nbins);
  coarse_hist_kernel<<<1024, 256, 0, stream>>>(edst, ccnt, E, sh_bin, nbins);
  coarse_scan_kernel<<<1, 256, 0, stream>>>(ccnt, bin_base, bin_cursor, nbins, E);
  binscatter_kernel<<<nb_bs, 256, 0, stream>>>(
      esrc, edst, etyp, bin_cursor, tmp, E, sh_bin, sh, nbins);
  finescatter_kernel<<<nbins, 1024, 0, stream>>>(
      tmp, bin_base, row_ptr, packed, N, E, sh_bin, sh);

  // ---- layers ----
  for (int l = 0; l < L; ++l) {
    const float* xin = (l == 0) ? x0 : A;
    float* outf      = (l == L - 1) ? (float*)d_out : A;

    compute_wt_kernel<<<nb_wt, 256, 0, stream>>>(
        basis + (size_t)l * Bn * DD * DD, coeff + (size_t)l * R * Bn,
        self_w + (size_t)l * DD * DD, Wt16, R, Bn);

    transform_h_kernel<<<nb_x, 256, 0, stream>>>(xin, Wt16, h16, N, R);

    aggregate_out_kernel<<<nb_agg, 256, 0, stream>>>(
        packed, row_ptr, h16, bias + (size_t)l * DD, outf, N, R);
  }
}

// Round 13
// 301.765 us; speedup vs baseline: 3.2754x; 1.0937x over previous
//
#include <hip/hip_runtime.h>
#include <hip/hip_bf16.h>

#define DD 64
#define EPB 8192   // edges per binscatter block (32 per thread)
#define WPAD 72    // padded LDS row stride (ushorts): 144B, 16B-aligned, ~2-way banks

typedef unsigned int u32;
typedef __attribute__((ext_vector_type(8))) short bf16x8;
typedef __attribute__((ext_vector_type(8))) unsigned short u16x8;
typedef __attribute__((ext_vector_type(4))) float f32x4;

__device__ __forceinline__ float bf2f(unsigned short u) {
  union { u32 i; float f; } c;
  c.i = ((u32)u) << 16;
  return c.f;
}
__device__ __forceinline__ unsigned short f2bf(float f) {
  __hip_bfloat16 h = __float2bfloat16(f);
  return *reinterpret_cast<unsigned short*>(&h);
}

// ---------------- preprocessing: two-level binned CSR build ----------------
// coarse bins: bn = dst >> sh_bin, nbins <= 256.
// tmp record: src | ty << sh | dlow << (sh+3)   (17+3+10 <= 32 bits)
// final packed record: rowid = ty*N + src  (direct h16 row index)

__global__ __launch_bounds__(256) void zero_u32_kernel(u32* __restrict__ p, int n) {
  int i = blockIdx.x * 256 + threadIdx.x;
  if (i < n) p[i] = 0u;
}

__global__ __launch_bounds__(256) void coarse_hist_kernel(
    const int* __restrict__ edst, u32* __restrict__ ccnt,
    int E, int sh_bin, int nbins) {
  __shared__ u32 lh[256];
  const int t = threadIdx.x;
  for (int j = t; j < nbins; j += 256) lh[j] = 0u;
  __syncthreads();
  for (int e = blockIdx.x * 256 + t; e < E; e += gridDim.x * 256)
    atomicAdd(&lh[edst[e] >> sh_bin], 1u);
  __syncthreads();
  for (int j = t; j < nbins; j += 256) {
    u32 c = lh[j];
    if (c) atomicAdd(&ccnt[j], c);
  }
}

__global__ __launch_bounds__(256) void coarse_scan_kernel(
    const u32* __restrict__ ccnt, u32* __restrict__ bin_base,
    u32* __restrict__ bin_cursor, int nbins, int E) {
  __shared__ u32 s[256];
  const int t = threadIdx.x;
  u32 v = (t < nbins) ? ccnt[t] : 0u;
  s[t] = v;
  __syncthreads();
  for (int off = 1; off < 256; off <<= 1) {
    u32 x = (t >= off) ? s[t - off] : 0u;
    __syncthreads();
    s[t] += x;
    __syncthreads();
  }
  if (t < nbins) {
    u32 ex = s[t] - v;
    bin_base[t] = ex;
    bin_cursor[t] = ex;
  }
  if (t == 0) bin_base[nbins] = (u32)E;
}

__global__ __launch_bounds__(256) void binscatter_kernel(
    const int* __restrict__ esrc, const int* __restrict__ edst,
    const int* __restrict__ et, u32* __restrict__ bin_cursor,
    u32* __restrict__ tmp, int E, int sh_bin, int sh, int nbins) {
  __shared__ u32 lhist[256];
  __shared__ u32 lbase[256];
  const int t = threadIdx.x;
  const int base = blockIdx.x * EPB;
  for (int j = t; j < nbins; j += 256) lhist[j] = 0u;
  __syncthreads();
  u32 br[32];
#pragma unroll
  for (int k = 0; k < 32; ++k) {
    int e = base + k * 256 + t;
    if (e < E) {
      int bn = edst[e] >> sh_bin;
      u32 r = atomicAdd(&lhist[bn], 1u);
      br[k] = ((u32)bn << 13) | r;           // bn<256, r<8192
    }
  }
  __syncthreads();
  for (int j = t; j < nbins; j += 256) {
    u32 c = lhist[j];
    lbase[j] = c ? atomicAdd(&bin_cursor[j], c) : 0u;
  }
  __syncthreads();
  const u32 wmask = (1u << sh_bin) - 1u;
#pragma unroll
  for (int k = 0; k < 32; ++k) {
    int e = base + k * 256 + t;
    if (e < E) {
      u32 bn = br[k] >> 13, r = br[k] & 0x1FFFu;
      u32 pos = lbase[bn] + r;
      u32 dlow = (u32)edst[e] & wmask;
      tmp[pos] = (u32)esrc[e] | ((u32)et[e] << sh) | (dlow << (sh + 3));
    }
  }
}

// One block per bin: LDS fine hist + scan -> row_ptr slice; emit rowid = ty*N+src.
__global__ __launch_bounds__(1024) void finescatter_kernel(
    const u32* __restrict__ tmp, const u32* __restrict__ bin_base,
    u32* __restrict__ row_ptr, u32* __restrict__ packed,
    int N, int E, int sh_bin, int sh) {
  __shared__ u32 dcnt[1024];
  __shared__ u32 s[1024];
  const int t = threadIdx.x;
  const int b = blockIdx.x;
  const u32 beg = bin_base[b], end = bin_base[b + 1];
  const int W  = 1 << sh_bin;
  const int d0 = b << sh_bin;
  const int dsh = sh + 3;
  const u32 smask = (1u << sh) - 1u;

  if (t < W) dcnt[t] = 0u;
  __syncthreads();
  for (u32 e = beg + t; e < end; e += 1024)
    atomicAdd(&dcnt[tmp[e] >> dsh], 1u);
  __syncthreads();
  u32 v = (t < W) ? dcnt[t] : 0u;
  s[t] = v;
  __syncthreads();
  for (int off = 1; off < 1024; off <<= 1) {
    u32 x = (t >= off) ? s[t - off] : 0u;
    __syncthreads();
    s[t] += x;
    __syncthreads();
  }
  const u32 ex = s[t] - v;
  if (t < W) {
    int d = d0 + t;
    if (d < N) row_ptr[d] = beg + ex;
    dcnt[t] = beg + ex;                      // cursor
  }
  if (b == 0 && t == 0) row_ptr[N] = (u32)E;
  __syncthreads();
  for (u32 e = beg + t; e < end; e += 1024) {
    u32 p = tmp[e];
    u32 pos = atomicAdd(&dcnt[p >> dsh], 1u);
    u32 src = p & smask;
    u32 ty  = (p >> sh) & 7u;
    packed[pos] = ty * (u32)N + src;         // direct h16 row index
  }
}

// ---------------- per-layer compute ----------------

// Wt16[m][o][k] = bf16( sum_b coeff[m,b]*basis[b,k,o] ) for m<R; self_w[k,o] for m==R.
__global__ __launch_bounds__(256) void compute_wt_kernel(
    const float* __restrict__ basis, const float* __restrict__ coeff,
    const float* __restrict__ self_w, unsigned short* __restrict__ Wt16,
    int R, int Bn) {
  int idx = blockIdx.x * 256 + threadIdx.x;
  int total = (R + 1) * DD * DD;
  if (idx >= total) return;
  int m = idx >> 12;
  int k = (idx >> 6) & 63;
  int o = idx & 63;
  float acc = 0.f;
  if (m == R) {
    acc = self_w[k * DD + o];
  } else {
    for (int b = 0; b < Bn; ++b)
      acc += coeff[m * Bn + b] * basis[((size_t)b * DD + k) * DD + o];
  }
  Wt16[((size_t)m * DD + o) * DD + k] = f2bf(acc);
}

// h16[m][node][pos] with PERMUTED row layout: value for output-feature
// f = t4*16 + kg*4 + j is stored at pos = kg*16 + t4*4 + j.
// This makes each lane's 16 outputs contiguous -> 2x16B stores (vs 4x8B).
// Aggregate un-permutes in its epilogue. x input is fp32 (layer0) or bf16 (layer1).
__global__ __launch_bounds__(256) void transform_h_kernel(
    const void* __restrict__ xin, int x_is_bf16,
    const unsigned short* __restrict__ Wt16,
    unsigned short* __restrict__ h16, int N, int R) {
  __shared__ unsigned short Ws[2][64 * WPAD];
  const int t    = threadIdx.x;
  const int w    = t >> 6;
  const int lane = t & 63;
  const int l16  = lane & 15;
  const int kg   = lane >> 4;
  const int node = blockIdx.x * DD + w * 16 + l16;   // B col = D col
  const bool ok  = (node < N);

  // X fragment (B operand): B[k][node]; lane reads features kg*8 + kc*32 .. +8
  bf16x8 Xfrag[2];
  if (x_is_bf16) {
    const unsigned short* xp =
        (const unsigned short*)xin + ((size_t)(ok ? node : 0) << 6) + kg * 8;
#pragma unroll
    for (int kc = 0; kc < 2; ++kc) {
      u16x8 v;
      if (ok) v = *reinterpret_cast<const u16x8*>(xp + kc * 32);
      else {
#pragma unroll
        for (int j = 0; j < 8; ++j) v[j] = 0;
      }
      Xfrag[kc] = *reinterpret_cast<bf16x8*>(&v);
    }
  } else {
    const float* xp = (const float*)xin + (size_t)(ok ? node : 0) * DD + kg * 8;
#pragma unroll
    for (int kc = 0; kc < 2; ++kc) {
      float4 v0 = ok ? *reinterpret_cast<const float4*>(xp + kc * 32)
                     : make_float4(0.f, 0.f, 0.f, 0.f);
      float4 v1 = ok ? *reinterpret_cast<const float4*>(xp + kc * 32 + 4)
                     : make_float4(0.f, 0.f, 0.f, 0.f);
      bf16x8 a;
      a[0] = (short)f2bf(v0.x); a[1] = (short)f2bf(v0.y);
      a[2] = (short)f2bf(v0.z); a[3] = (short)f2bf(v0.w);
      a[4] = (short)f2bf(v1.x); a[5] = (short)f2bf(v1.y);
      a[6] = (short)f2bf(v1.z); a[7] = (short)f2bf(v1.w);
      Xfrag[kc] = a;
    }
  }

  // stage m=0 into buffer 0 (32B/thread, coalesced)
  {
#pragma unroll
    for (int i = 0; i < 2; ++i) {
      int q = t + (i << 8);                 // 0..511
      int row = q >> 3, c8 = (q & 7) << 3;  // 64 rows x 8 chunks of 8 ushorts
      u16x8 v = *reinterpret_cast<const u16x8*>(Wt16 + row * DD + c8);
      *reinterpret_cast<u16x8*>(&Ws[0][row * WPAD + c8]) = v;
    }
  }
  __syncthreads();

  for (int m = 0; m <= R; ++m) {
    const int cur = m & 1;
    // issue next matrix staging first: global latency hides under this m's MFMAs
    if (m < R) {
      const unsigned short* wb = Wt16 + ((size_t)(m + 1) << 12);
#pragma unroll
      for (int i = 0; i < 2; ++i) {
        int q = t + (i << 8);
        int row = q >> 3, c8 = (q & 7) << 3;
        u16x8 v = *reinterpret_cast<const u16x8*>(wb + row * DD + c8);
        *reinterpret_cast<u16x8*>(&Ws[cur ^ 1][row * WPAD + c8]) = v;
      }
    }

    // compute all 4 t4-tiles, then two contiguous 16B stores
    f32x4 acc[4];
#pragma unroll
    for (int t4 = 0; t4 < 4; ++t4) {
      const unsigned short* ap = &Ws[cur][(t4 * 16 + l16) * WPAD + kg * 8];
      bf16x8 A0 = *reinterpret_cast<const bf16x8*>(ap);
      bf16x8 A1 = *reinterpret_cast<const bf16x8*>(ap + 32);
      acc[t4][0] = 0.f; acc[t4][1] = 0.f; acc[t4][2] = 0.f; acc[t4][3] = 0.f;
      acc[t4] = __builtin_amdgcn_mfma_f32_16x16x32_bf16(A0, Xfrag[0], acc[t4], 0, 0, 0);
      acc[t4] = __builtin_amdgcn_mfma_f32_16x16x32_bf16(A1, Xfrag[1], acc[t4], 0, 0, 0);
    }
    if (ok) {
      unsigned short* hp = h16 + (((size_t)m * N + node) << 6) + kg * 16;
      u16x8 o0, o1;
#pragma unroll
      for (int j = 0; j < 4; ++j) {
        o0[j]     = f2bf(acc[0][j]);   // pos kg*16 + 0..3  (t4=0)
        o0[4 + j] = f2bf(acc[1][j]);   // pos kg*16 + 4..7  (t4=1)
        o1[j]     = f2bf(acc[2][j]);   // pos kg*16 + 8..11 (t4=2)
        o1[4 + j] = f2bf(acc[3][j]);   // pos kg*16 +12..15 (t4=3)
      }
      *reinterpret_cast<u16x8*>(hp) = o0;
      *reinterpret_cast<u16x8*>(hp + 8) = o1;
    }
    __syncthreads();   // staging of m+1 done; reads of buf[cur] done before reuse
  }
}

// One wave per destination node. 8 groups x 8 lanes; group g handles edge e+g,
// lane loads ushort8 (16B) = stored positions l8*8..+7. Epilogue un-permutes:
// pos p -> feature ((p>>2)&3)*16 + (p>>4)*4 + (p&3); lane l8 owns features
// [f_lo,f_lo+4) and [f_lo+16,f_lo+20), f_lo = (l8&1)*32 + (l8>>1)*4.
// Output: bf16 (layer 0 activation) or fp32 (final d_out).
__global__ __launch_bounds__(256) void aggregate_out_kernel(
    const u32* __restrict__ packed, const u32* __restrict__ row_ptr,
    const unsigned short* __restrict__ h16, const float* __restrict__ bias_l,
    void* __restrict__ outv, int out_is_bf16, int N, int R) {
  const int wid  = (blockIdx.x * 256 + threadIdx.x) >> 6;
  const int lane = threadIdx.x & 63;
  if (wid >= N) return;
  const int g  = lane >> 3;      // 0..7: edge slot
  const int l8 = lane & 7;       // 16B chunk within row
  const u32 beg = row_ptr[wid], end = row_ptr[wid + 1];

  float s[8];
  if (g == 0) {                  // self row, counted once
    u16x8 v = *reinterpret_cast<const u16x8*>(
        h16 + (((size_t)R * N + wid) << 6) + l8 * 8);
#pragma unroll
    for (int j = 0; j < 8; ++j) s[j] = bf2f((unsigned short)v[j]);
  } else {
#pragma unroll
    for (int j = 0; j < 8; ++j) s[j] = 0.f;
  }

  const u32 cnt = end - beg;
  u32 e = beg;
  const u32 end16 = beg + (cnt & ~15u);
  for (; e < end16; e += 16) {   // two 1KB gathers in flight
    u32 r0 = packed[e + g];
    u32 r1 = packed[e + 8 + g];
    u16x8 v0 = *reinterpret_cast<const u16x8*>(h16 + ((size_t)r0 << 6) + l8 * 8);
    u16x8 v1 = *reinterpret_cast<const u16x8*>(h16 + ((size_t)r1 << 6) + l8 * 8);
#pragma unroll
    for (int j = 0; j < 8; ++j)
      s[j] += bf2f((unsigned short)v0[j]) + bf2f((unsigned short)v1[j]);
  }
  if (e + 8 <= end) {
    u32 r0 = packed[e + g];
    u16x8 v0 = *reinterpret_cast<const u16x8*>(h16 + ((size_t)r0 << 6) + l8 * 8);
#pragma unroll
    for (int j = 0; j < 8; ++j) s[j] += bf2f((unsigned short)v0[j]);
    e += 8;
  }
  if (e < end) {                 // masked tail (<8 edges)
    u32 eg = e + g;
    if (eg < end) {
      u32 r0 = packed[eg];
      u16x8 v0 = *reinterpret_cast<const u16x8*>(h16 + ((size_t)r0 << 6) + l8 * 8);
#pragma unroll
      for (int j = 0; j < 8; ++j) s[j] += bf2f((unsigned short)v0[j]);
    }
  }

  // reduce across the 8 edge-groups (lanes with same l8)
#pragma unroll
  for (int j = 0; j < 8; ++j) {
    s[j] += __shfl_xor(s[j], 8);
    s[j] += __shfl_xor(s[j], 16);
    s[j] += __shfl_xor(s[j], 32);
  }

  if (g == 0) {
    const int f_lo = ((l8 & 1) << 5) | ((l8 >> 1) << 2);
    const int f_hi = f_lo + 16;
    const float4 blo = *reinterpret_cast<const float4*>(bias_l + f_lo);
    const float4 bhi = *reinterpret_cast<const float4*>(bias_l + f_hi);
    // s[0..3] -> features f_lo..f_lo+3 ; s[4..7] -> f_hi..f_hi+3
    float r0 = fmaxf(s[0] + blo.x, 0.f), r1 = fmaxf(s[1] + blo.y, 0.f);
    float r2 = fmaxf(s[2] + blo.z, 0.f), r3 = fmaxf(s[3] + blo.w, 0.f);
    float r4 = fmaxf(s[4] + bhi.x, 0.f), r5 = fmaxf(s[5] + bhi.y, 0.f);
    float r6 = fmaxf(s[6] + bhi.z, 0.f), r7 = fmaxf(s[7] + bhi.w, 0.f);
    if (out_is_bf16) {
      unsigned short* op = (unsigned short*)outv + ((size_t)wid << 6);
      ushort4 a, b;
      a.x = f2bf(r0); a.y = f2bf(r1); a.z = f2bf(r2); a.w = f2bf(r3);
      b.x = f2bf(r4); b.y = f2bf(r5); b.z = f2bf(r6); b.w = f2bf(r7);
      *reinterpret_cast<ushort4*>(op + f_lo) = a;
      *reinterpret_cast<ushort4*>(op + f_hi) = b;
    } else {
      float* op = (float*)outv + ((size_t)wid << 6);
      float4 a = make_float4(r0, r1, r2, r3);
      float4 b = make_float4(r4, r5, r6, r7);
      *reinterpret_cast<float4*>(op + f_lo) = a;
      *reinterpret_cast<float4*>(op + f_hi) = b;
    }
  }
}

extern "C" void kernel_launch(void* const* d_in, const int* in_sizes, int n_in,
                              void* d_out, int out_size, void* d_ws, size_t ws_size,
                              hipStream_t stream) {
  const float* x0     = (const float*)d_in[0];
  const float* basis  = (const float*)d_in[1];
  const float* coeff  = (const float*)d_in[2];
  const float* self_w = (const float*)d_in[3];
  const float* bias   = (const float*)d_in[4];
  const int*   eidx   = (const int*)d_in[5];
  const int*   etyp   = (const int*)d_in[6];

  const int N  = in_sizes[0] / DD;
  const int L  = in_sizes[4] / DD;
  const int Bn = in_sizes[1] / (L * DD * DD);
  const int R  = in_sizes[2] / (L * Bn);
  const int E  = in_sizes[6];

  int sh = 0;
  while ((1 << sh) < N) ++sh;               // src bits (17 at N=100k)
  int sh_bin = 0;
  while ((((N - 1) >> sh_bin) + 1) > 256) ++sh_bin;    // nbins<=256 (sh_bin=9)
  const int nbins = ((N - 1) >> sh_bin) + 1;           // 196 at N=100k

  const int* esrc = eidx;
  const int* edst = eidx + E;

  // ---- workspace layout ----
  u32* row_ptr = (u32*)d_ws;                               // N+1
  u32* packed  = row_ptr + N + 1;                          // E
  size_t u32B  = (((size_t)N + 1 + E) * 4 + 15) / 16 * 16;
  unsigned short* Wt16 = (unsigned short*)((char*)d_ws + u32B);   // (R+1)*DD*DD
  size_t wtB   = (u32B + (size_t)(R + 1) * DD * DD * 2 + 15) / 16 * 16;
  unsigned short* A16 = (unsigned short*)((char*)d_ws + wtB);     // N*DD bf16 activation
  unsigned short* h16 = A16 + ((size_t)N << 6);            // (R+1)*N*DD bf16
  // build-phase overlays on h16 region
  u32* ccnt       = (u32*)h16;                             // nbins
  u32* bin_base   = ccnt + 256;                            // nbins+1
  u32* bin_cursor = bin_base + 257;                        // nbins
  u32* tmp        = bin_cursor + 256 + 3;                  // E

  const int nb_bs  = (E + EPB - 1) / EPB;
  const int nb_agg = (int)(((size_t)N * 64 + 255) / 256);
  const int nb_x   = (N + DD - 1) / DD;
  const int nb_wt  = ((R + 1) * DD * DD + 255) / 256;

  // ---- build CSR (once; edges constant across layers) ----
  zero_u32_kernel<<<1, 256, 0, stream>>>(ccnt, nbins);
  coarse_hist_kernel<<<1024, 256, 0, stream>>>(edst, ccnt, E, sh_bin, nbins);
  coarse_scan_kernel<<<1, 256, 0, stream>>>(ccnt, bin_base, bin_cursor, nbins, E);
  binscatter_kernel<<<nb_bs, 256, 0, stream>>>(
      esrc, edst, etyp, bin_cursor, tmp, E, sh_bin, sh, nbins);
  finescatter_kernel<<<nbins, 1024, 0, stream>>>(
      tmp, bin_base, row_ptr, packed, N, E, sh_bin, sh);

  // ---- layers ----
  for (int l = 0; l < L; ++l) {
    compute_wt_kernel<<<nb_wt, 256, 0, stream>>>(
        basis + (size_t)l * Bn * DD * DD, coeff + (size_t)l * R * Bn,
        self_w + (size_t)l * DD * DD, Wt16, R, Bn);

    if (l == 0) {
      transform_h_kernel<<<nb_x, 256, 0, stream>>>(x0, 0, Wt16, h16, N, R);
    } else {
      transform_h_kernel<<<nb_x, 256, 0, stream>>>(A16, 1, Wt16, h16, N, R);
    }

    if (l == L - 1) {
      aggregate_out_kernel<<<nb_agg, 256, 0, stream>>>(
          packed, row_ptr, h16, bias + (size_t)l * DD, d_out, 0, N, R);
    } else {
      aggregate_out_kernel<<<nb_agg, 256, 0, stream>>>(
          packed, row_ptr, h16, bias + (size_t)l * DD, A16, 1, N, R);
    }
  }
}